// Round 1
// baseline (536.995 us; speedup 1.0000x reference)
//
#include <hip/hip_runtime.h>
#include <math.h>

#define B_ 4
#define S_ 2048
#define D_ 1024
#define M_ 512
#define H_ 8
#define R_ (B_ * S_)  // 8192

typedef __bf16 bf8_t __attribute__((ext_vector_type(8)));
typedef __bf16 bf4_t __attribute__((ext_vector_type(4)));
typedef float f4_t __attribute__((ext_vector_type(4)));

// ---------------- x (fp32) -> bf16, written into ab[:, 0:1024] with row stride 1536
__global__ __launch_bounds__(256) void k_convert_x(const float* __restrict__ x,
                                                   __bf16* __restrict__ ab) {
  size_t i = ((size_t)blockIdx.x * 256 + threadIdx.x) * 8;  // over R*1024
  size_t row = i >> 10;
  size_t col = i & 1023;
  f4_t f0 = *(const f4_t*)(x + i);
  f4_t f1 = *(const f4_t*)(x + i + 4);
  bf8_t v;
  v[0] = (__bf16)f0[0]; v[1] = (__bf16)f0[1]; v[2] = (__bf16)f0[2]; v[3] = (__bf16)f0[3];
  v[4] = (__bf16)f1[0]; v[5] = (__bf16)f1[1]; v[6] = (__bf16)f1[2]; v[7] = (__bf16)f1[3];
  *(bf8_t*)(ab + row * 1536 + col) = v;
}

// ---------------- W[K][N] fp32 -> Wt[N][K] bf16 (tiled transpose)
__global__ void k_transpose(const float* __restrict__ in, __bf16* __restrict__ out,
                            int K, int N) {
  __shared__ float tile[32][33];
  const int n0 = blockIdx.x * 32;
  const int k0 = blockIdx.y * 32;
  const int tx = threadIdx.x;  // 0..31
  const int ty = threadIdx.y;  // 0..7
#pragma unroll
  for (int j = 0; j < 32; j += 8)
    tile[ty + j][tx] = in[(size_t)(k0 + ty + j) * N + n0 + tx];
  __syncthreads();
#pragma unroll
  for (int j = 0; j < 32; j += 8)
    out[(size_t)(n0 + ty + j) * K + k0 + tx] = (__bf16)tile[tx][ty + j];
}

// ---------------- GEMM: C[m][n] = sum_k A[m][k] * Bt[n][k] + bias[n]; EPI 1 = exact GELU
// A bf16 [Mrows x K] (lda), Bt bf16 [N][K], C bf16 (ldc). Tiles 128x128, BK=32, 4 waves.
template <int EPI>
__global__ __launch_bounds__(256) void k_gemm_bt(const __bf16* __restrict__ A, int lda,
                                                 const __bf16* __restrict__ Bt,
                                                 const float* __restrict__ bias,
                                                 __bf16* __restrict__ C, int ldc, int K) {
  __shared__ __bf16 As[128][40];
  __shared__ __bf16 Bs[128][40];
  const int t = threadIdx.x;
  const int lane = t & 63;
  const int wv = t >> 6;
  const int wr = (wv >> 1) * 64;
  const int wc = (wv & 1) * 64;
  const int bm = blockIdx.y * 128;
  const int bn = blockIdx.x * 128;
  const int ar = t >> 1;        // staging row 0..127
  const int ac = (t & 1) * 16;  // staging col 0/16
  const __bf16* Ap = A + (size_t)(bm + ar) * lda + ac;
  const __bf16* Bp = Bt + (size_t)(bn + ar) * (size_t)K + ac;
  f4_t acc[4][4];
#pragma unroll
  for (int m = 0; m < 4; ++m)
#pragma unroll
    for (int n = 0; n < 4; ++n) acc[m][n] = (f4_t){0.f, 0.f, 0.f, 0.f};
  const int fr = lane & 15;
  const int fk = (lane >> 4) * 8;
  for (int k0 = 0; k0 < K; k0 += 32) {
    bf8_t a0 = *(const bf8_t*)(Ap + k0);
    bf8_t a1 = *(const bf8_t*)(Ap + k0 + 8);
    bf8_t b0 = *(const bf8_t*)(Bp + k0);
    bf8_t b1 = *(const bf8_t*)(Bp + k0 + 8);
    __syncthreads();
    *(bf8_t*)&As[ar][ac] = a0;
    *(bf8_t*)&As[ar][ac + 8] = a1;
    *(bf8_t*)&Bs[ar][ac] = b0;
    *(bf8_t*)&Bs[ar][ac + 8] = b1;
    __syncthreads();
    bf8_t af[4], bfr[4];
#pragma unroll
    for (int m = 0; m < 4; ++m) af[m] = *(const bf8_t*)&As[wr + m * 16 + fr][fk];
#pragma unroll
    for (int n = 0; n < 4; ++n) bfr[n] = *(const bf8_t*)&Bs[wc + n * 16 + fr][fk];
#pragma unroll
    for (int m = 0; m < 4; ++m)
#pragma unroll
      for (int n = 0; n < 4; ++n)
        acc[m][n] = __builtin_amdgcn_mfma_f32_16x16x32_bf16(af[m], bfr[n], acc[m][n], 0, 0, 0);
  }
  const int cr = (lane >> 4) * 4;
  const int cc = lane & 15;
#pragma unroll
  for (int n = 0; n < 4; ++n) {
    const int col = bn + wc + n * 16 + cc;
    const float bv = bias[col];
#pragma unroll
    for (int m = 0; m < 4; ++m)
#pragma unroll
      for (int r = 0; r < 4; ++r) {
        const int row = bm + wr + m * 16 + cr + r;
        float v = acc[m][n][r] + bv;
        if (EPI == 1) v = 0.5f * v * (1.0f + erff(v * 0.70710678118f));
        C[(size_t)row * ldc + col] = (__bf16)v;
      }
  }
}

// ---------------- flash attention: one block per (b, h, 64-query tile); 4 waves x 16 q.
__global__ __launch_bounds__(256) void k_attn(const __bf16* __restrict__ qb,
                                              const __bf16* __restrict__ kb,
                                              const __bf16* __restrict__ vb,
                                              const float* __restrict__ ocr_bias,
                                              __bf16* __restrict__ ctx) {
  __shared__ __bf16 Ks[32][72];      // K chunk, row = key, col = d (padded)
  __shared__ __bf16 Vt[64][40];      // V^T chunk, row = d, col = key (padded)
  __shared__ __bf16 Pl[4][16][40];   // per-wave P tile [q][k]
  const int t = threadIdx.x;
  const int lane = t & 63;
  const int wv = t >> 6;
  const int qt = blockIdx.x;  // 0..31
  const int h = blockIdx.y;   // 0..7
  const int b = blockIdx.z;   // 0..3
  const int q0 = qt * 64 + wv * 16;
  const int fr = lane & 15;
  const int fk = (lane >> 4) * 8;
  // Q fragments (A-operand, K=64 split into 2 slices of 32)
  const size_t rowQ = ((size_t)b * S_ + q0 + fr) * M_ + h * 64;
  const bf8_t aq0 = *(const bf8_t*)(qb + rowQ + fk);
  const bf8_t aq1 = *(const bf8_t*)(qb + rowQ + 32 + fk);
  float mr[4], lr[4];
  f4_t o[4];
#pragma unroll
  for (int r = 0; r < 4; ++r) { mr[r] = -1e30f; lr[r] = 0.f; }
#pragma unroll
  for (int d = 0; d < 4; ++d) o[d] = (f4_t){0.f, 0.f, 0.f, 0.f};
  const float sc = 0.125f;  // 1/sqrt(64)
  const float hb = ocr_bias[h];
  const int sr = t >> 3;        // staging key row 0..31
  const int scc = (t & 7) * 8;  // staging col 0..56
  const size_t kvbase = ((size_t)b * S_) * M_ + h * 64;

  for (int kv0 = 0; kv0 < S_; kv0 += 32) {
    __syncthreads();
    {
      bf8_t kk = *(const bf8_t*)(kb + kvbase + (size_t)(kv0 + sr) * M_ + scc);
      bf8_t vvv = *(const bf8_t*)(vb + kvbase + (size_t)(kv0 + sr) * M_ + scc);
      *(bf8_t*)&Ks[sr][scc] = kk;
#pragma unroll
      for (int e = 0; e < 8; ++e) Vt[scc + e][sr] = vvv[e];
    }
    __syncthreads();
    // QK^T: two 16-key halves
    f4_t s0 = (f4_t){0.f, 0.f, 0.f, 0.f};
    f4_t s1 = (f4_t){0.f, 0.f, 0.f, 0.f};
    {
      bf8_t k00 = *(const bf8_t*)&Ks[fr][fk];
      bf8_t k01 = *(const bf8_t*)&Ks[fr][32 + fk];
      bf8_t k10 = *(const bf8_t*)&Ks[16 + fr][fk];
      bf8_t k11 = *(const bf8_t*)&Ks[16 + fr][32 + fk];
      s0 = __builtin_amdgcn_mfma_f32_16x16x32_bf16(aq0, k00, s0, 0, 0, 0);
      s0 = __builtin_amdgcn_mfma_f32_16x16x32_bf16(aq1, k01, s0, 0, 0, 0);
      s1 = __builtin_amdgcn_mfma_f32_16x16x32_bf16(aq0, k10, s1, 0, 0, 0);
      s1 = __builtin_amdgcn_mfma_f32_16x16x32_bf16(aq1, k11, s1, 0, 0, 0);
    }
    float p0[4], p1[4], tm[4], ts[4], al[4];
#pragma unroll
    for (int r = 0; r < 4; ++r) {
      p0[r] = s0[r] * sc + hb;
      p1[r] = s1[r] * sc + hb;
      tm[r] = fmaxf(p0[r], p1[r]);
    }
#pragma unroll
    for (int d = 1; d < 16; d <<= 1)
#pragma unroll
      for (int r = 0; r < 4; ++r) tm[r] = fmaxf(tm[r], __shfl_xor(tm[r], d, 64));
#pragma unroll
    for (int r = 0; r < 4; ++r) {
      const float mn = fmaxf(mr[r], tm[r]);
      al[r] = __expf(mr[r] - mn);
      mr[r] = mn;
      p0[r] = __expf(p0[r] - mn);
      p1[r] = __expf(p1[r] - mn);
      ts[r] = p0[r] + p1[r];
    }
#pragma unroll
    for (int d = 1; d < 16; d <<= 1)
#pragma unroll
      for (int r = 0; r < 4; ++r) ts[r] += __shfl_xor(ts[r], d, 64);
#pragma unroll
    for (int r = 0; r < 4; ++r) lr[r] = lr[r] * al[r] + ts[r];
#pragma unroll
    for (int d = 0; d < 4; ++d)
#pragma unroll
      for (int r = 0; r < 4; ++r) o[d][r] *= al[r];
    // write P (bf16) to per-wave LDS: row = query, col = key-in-chunk
    {
      const int pr = (lane >> 4) * 4;
#pragma unroll
      for (int r = 0; r < 4; ++r) {
        Pl[wv][pr + r][fr] = (__bf16)p0[r];
        Pl[wv][pr + r][16 + fr] = (__bf16)p1[r];
      }
    }
    // PV: O += P[16x32] * V[32x64]
    {
      const bf8_t ap = *(const bf8_t*)&Pl[wv][fr][fk];
#pragma unroll
      for (int d = 0; d < 4; ++d) {
        bf8_t bvv = *(const bf8_t*)&Vt[d * 16 + fr][fk];
        o[d] = __builtin_amdgcn_mfma_f32_16x16x32_bf16(ap, bvv, o[d], 0, 0, 0);
      }
    }
  }
  // epilogue: divide by row sums, write ctx
  const int pr = (lane >> 4) * 4;
#pragma unroll
  for (int d = 0; d < 4; ++d)
#pragma unroll
    for (int r = 0; r < 4; ++r) {
      const float v = o[d][r] / lr[r];
      ctx[((size_t)b * S_ + q0 + pr + r) * M_ + h * 64 + d * 16 + fr] = (__bf16)v;
    }
}

// ---------------- LayerNorm over D=1024, one block per row
__global__ __launch_bounds__(256) void k_ln(const __bf16* __restrict__ hh,
                                            const float* __restrict__ g,
                                            const float* __restrict__ bt,
                                            float* __restrict__ out) {
  const int row = blockIdx.x;
  const int t = threadIdx.x;
  const __bf16* hp = hh + (size_t)row * 1024 + t * 4;
  bf4_t v = *(const bf4_t*)hp;
  float f[4];
  float s1 = 0.f, s2 = 0.f;
#pragma unroll
  for (int j = 0; j < 4; ++j) {
    f[j] = (float)v[j];
    s1 += f[j];
    s2 += f[j] * f[j];
  }
#pragma unroll
  for (int d = 1; d < 64; d <<= 1) {
    s1 += __shfl_xor(s1, d, 64);
    s2 += __shfl_xor(s2, d, 64);
  }
  __shared__ float red[8];
  const int lane = t & 63, wv = t >> 6;
  if (lane == 0) { red[wv] = s1; red[4 + wv] = s2; }
  __syncthreads();
  const float S1 = red[0] + red[1] + red[2] + red[3];
  const float S2 = red[4] + red[5] + red[6] + red[7];
  const float mu = S1 * (1.f / 1024.f);
  const float var = S2 * (1.f / 1024.f) - mu * mu;
  const float inv = rsqrtf(var + 1e-5f);
  float* op = out + (size_t)row * 1024 + t * 4;
#pragma unroll
  for (int j = 0; j < 4; ++j) op[j] = (f[j] - mu) * inv * g[t * 4 + j] + bt[t * 4 + j];
}

extern "C" void kernel_launch(void* const* d_in, const int* in_sizes, int n_in,
                              void* d_out, int out_size, void* d_ws, size_t ws_size,
                              hipStream_t stream) {
  const float* x = (const float*)d_in[0];
  const float* W_enc = (const float*)d_in[1];
  const float* b_enc = (const float*)d_in[2];
  const float* Wq = (const float*)d_in[3];
  const float* bq = (const float*)d_in[4];
  const float* Wk = (const float*)d_in[5];
  const float* bk = (const float*)d_in[6];
  const float* Wv = (const float*)d_in[7];
  const float* bv = (const float*)d_in[8];
  const float* Wo = (const float*)d_in[9];
  const float* bo = (const float*)d_in[10];
  const float* ocr = (const float*)d_in[11];
  const float* W1 = (const float*)d_in[12];
  const float* b1 = (const float*)d_in[13];
  const float* W2 = (const float*)d_in[14];
  const float* b2 = (const float*)d_in[15];
  const float* lng = (const float*)d_in[16];
  const float* lnb = (const float*)d_in[17];
  float* out = (float*)d_out;

  __bf16* p = (__bf16*)d_ws;
  __bf16* ab = p;  p += (size_t)R_ * 1536;   // [x | attended] bf16, stride 1536
  __bf16* mem = p; p += (size_t)R_ * 512;
  __bf16* qb = p;  p += (size_t)R_ * 512;
  __bf16* kb = p;  p += (size_t)R_ * 512;
  __bf16* vbuf = p; p += (size_t)R_ * 512;
  __bf16* cx = p;  p += (size_t)R_ * 512;
  __bf16* h1 = p;  p += (size_t)R_ * 1024;
  __bf16* h2 = p;  p += (size_t)R_ * 1024;
  __bf16* WtE = p; p += (size_t)512 * 1024;
  __bf16* WtQ = p; p += (size_t)512 * 512;
  __bf16* WtK = p; p += (size_t)512 * 512;
  __bf16* WtV = p; p += (size_t)512 * 512;
  __bf16* WtO = p; p += (size_t)512 * 512;
  __bf16* Wt1 = p; p += (size_t)1024 * 1536;
  __bf16* Wt2 = p; p += (size_t)1024 * 1024;

  // 1) convert x -> ab[:, :1024]
  k_convert_x<<<4096, 256, 0, stream>>>(x, ab);
  // 2) transpose+convert all weights
  dim3 tb(32, 8);
  k_transpose<<<dim3(16, 32), tb, 0, stream>>>(W_enc, WtE, 1024, 512);
  k_transpose<<<dim3(16, 16), tb, 0, stream>>>(Wq, WtQ, 512, 512);
  k_transpose<<<dim3(16, 16), tb, 0, stream>>>(Wk, WtK, 512, 512);
  k_transpose<<<dim3(16, 16), tb, 0, stream>>>(Wv, WtV, 512, 512);
  k_transpose<<<dim3(16, 16), tb, 0, stream>>>(Wo, WtO, 512, 512);
  k_transpose<<<dim3(32, 48), tb, 0, stream>>>(W1, Wt1, 1536, 1024);
  k_transpose<<<dim3(32, 32), tb, 0, stream>>>(W2, Wt2, 1024, 1024);
  // 3) mem = x @ W_enc + b_enc
  k_gemm_bt<0><<<dim3(4, 64), 256, 0, stream>>>(ab, 1536, WtE, b_enc, mem, 512, 1024);
  // 4) q,k,v
  k_gemm_bt<0><<<dim3(4, 64), 256, 0, stream>>>(mem, 512, WtQ, bq, qb, 512, 512);
  k_gemm_bt<0><<<dim3(4, 64), 256, 0, stream>>>(mem, 512, WtK, bk, kb, 512, 512);
  k_gemm_bt<0><<<dim3(4, 64), 256, 0, stream>>>(mem, 512, WtV, bv, vbuf, 512, 512);
  // 5) attention -> cx
  k_attn<<<dim3(32, 8, 4), 256, 0, stream>>>(qb, kb, vbuf, ocr, cx);
  // 6) attended = cx @ Wo + bo  -> ab[:, 1024:1536]
  k_gemm_bt<0><<<dim3(4, 64), 256, 0, stream>>>(cx, 512, WtO, bo, ab + 1024, 1536, 512);
  // 7) h1 = gelu([x|att] @ W1 + b1)
  k_gemm_bt<1><<<dim3(8, 64), 256, 0, stream>>>(ab, 1536, Wt1, b1, h1, 1024, 1536);
  // 8) h2 = h1 @ W2 + b2
  k_gemm_bt<0><<<dim3(8, 64), 256, 0, stream>>>(h1, 1024, Wt2, b2, h2, 1024, 1024);
  // 9) layernorm -> out (fp32)
  k_ln<<<R_, 256, 0, stream>>>(h2, lng, lnb, out);
}

// Round 2
// 433.652 us; speedup vs baseline: 1.2383x; 1.2383x over previous
//
#include <hip/hip_runtime.h>
#include <math.h>

#define B_ 4
#define S_ 2048
#define D_ 1024
#define M_ 512
#define H_ 8
#define R_ (B_ * S_)  // 8192

typedef __bf16 bf8_t __attribute__((ext_vector_type(8)));
typedef __bf16 bf4_t __attribute__((ext_vector_type(4)));
typedef float f4_t __attribute__((ext_vector_type(4)));

typedef __attribute__((address_space(3))) void lds_void;
typedef const __attribute__((address_space(1))) void gl_void;
#define GL16(gp, lp) __builtin_amdgcn_global_load_lds((gl_void*)(gp), (lds_void*)(lp), 16, 0, 0)

__device__ inline unsigned packbf2(float a, float b) {
  union { __bf16 h[2]; unsigned u; } c;
  c.h[0] = (__bf16)a;
  c.h[1] = (__bf16)b;
  return c.u;
}
__device__ inline unsigned bperm(int srcBytes, unsigned v) {
  return (unsigned)__builtin_amdgcn_ds_bpermute(srcBytes, (int)v);
}

// ---------------- x (fp32) -> bf16, written into ab[:, 0:1024] with row stride 1536
__global__ __launch_bounds__(256) void k_convert_x(const float* __restrict__ x,
                                                   __bf16* __restrict__ ab) {
  size_t i = ((size_t)blockIdx.x * 256 + threadIdx.x) * 8;  // over R*1024
  size_t row = i >> 10;
  size_t col = i & 1023;
  f4_t f0 = *(const f4_t*)(x + i);
  f4_t f1 = *(const f4_t*)(x + i + 4);
  bf8_t v;
  v[0] = (__bf16)f0[0]; v[1] = (__bf16)f0[1]; v[2] = (__bf16)f0[2]; v[3] = (__bf16)f0[3];
  v[4] = (__bf16)f1[0]; v[5] = (__bf16)f1[1]; v[6] = (__bf16)f1[2]; v[7] = (__bf16)f1[3];
  *(bf8_t*)(ab + row * 1536 + col) = v;
}

// ---------------- W[K][N] fp32 -> Wt[N][K] bf16 (tiled transpose)
__global__ void k_transpose(const float* __restrict__ in, __bf16* __restrict__ out,
                            int K, int N) {
  __shared__ float tile[32][33];
  const int n0 = blockIdx.x * 32;
  const int k0 = blockIdx.y * 32;
  const int tx = threadIdx.x;  // 0..31
  const int ty = threadIdx.y;  // 0..7
#pragma unroll
  for (int j = 0; j < 32; j += 8)
    tile[ty + j][tx] = in[(size_t)(k0 + ty + j) * N + n0 + tx];
  __syncthreads();
#pragma unroll
  for (int j = 0; j < 32; j += 8)
    out[(size_t)(n0 + ty + j) * K + k0 + tx] = (__bf16)tile[tx][ty + j];
}

// ---------------- GEMM: C[m][n] = sum_k A[m][k] * Bt[n][k] + bias[n]
// EPI 0: plain bf16 store. EPI 1: exact GELU. EPI 2: write transposed-per-batch
// (V^T: out[(batch*512 + col)*2048 + (row&2047)]).
// A bf16 [Mrows x K] (lda), Bt bf16 [N][K]. Tiles 128x128, BK=32, 4 waves.
// m97 structure: global_load_lds width-16 into linear LDS, 2 barriers / K-step.
template <int EPI>
__global__ __launch_bounds__(256) void k_gemm_bt(const __bf16* __restrict__ A, int lda,
                                                 const __bf16* __restrict__ Bt,
                                                 const float* __restrict__ bias,
                                                 __bf16* __restrict__ C, int ldc, int K) {
  __shared__ __bf16 As[128 * 32];
  __shared__ __bf16 Bs[128 * 32];
  const int t = threadIdx.x;
  const int lane = t & 63;
  const int wv = t >> 6;
  const int wr = (wv >> 1) * 64;
  const int wc = (wv & 1) * 64;
  const int bm = blockIdx.y * 128;
  const int bn = blockIdx.x * 128;
  // staging: chunk c = wv*2+i covers rows [c*16, c*16+16), 1KB each
  const int c0 = wv * 2, c1 = wv * 2 + 1;
  const int sr0 = c0 * 16 + (lane >> 2);
  const int sr1 = c1 * 16 + (lane >> 2);
  const int scol = (lane & 3) * 8;
  const __bf16* Ag0 = A + (size_t)(bm + sr0) * lda + scol;
  const __bf16* Ag1 = A + (size_t)(bm + sr1) * lda + scol;
  const __bf16* Bg0 = Bt + (size_t)(bn + sr0) * (size_t)K + scol;
  const __bf16* Bg1 = Bt + (size_t)(bn + sr1) * (size_t)K + scol;
  __bf16* Al0 = As + c0 * 512;  // wave-uniform LDS bases
  __bf16* Al1 = As + c1 * 512;
  __bf16* Bl0 = Bs + c0 * 512;
  __bf16* Bl1 = Bs + c1 * 512;
  f4_t acc[4][4];
#pragma unroll
  for (int m = 0; m < 4; ++m)
#pragma unroll
    for (int n = 0; n < 4; ++n) acc[m][n] = (f4_t){0.f, 0.f, 0.f, 0.f};
  const int fr = lane & 15;
  const int fk = (lane >> 4) * 8;
  for (int k0 = 0; k0 < K; k0 += 32) {
    __syncthreads();
    GL16(Ag0 + k0, Al0);
    GL16(Ag1 + k0, Al1);
    GL16(Bg0 + k0, Bl0);
    GL16(Bg1 + k0, Bl1);
    __syncthreads();
    bf8_t af[4], bfr[4];
#pragma unroll
    for (int m = 0; m < 4; ++m) af[m] = *(const bf8_t*)&As[(wr + m * 16 + fr) * 32 + fk];
#pragma unroll
    for (int n = 0; n < 4; ++n) bfr[n] = *(const bf8_t*)&Bs[(wc + n * 16 + fr) * 32 + fk];
#pragma unroll
    for (int m = 0; m < 4; ++m)
#pragma unroll
      for (int n = 0; n < 4; ++n)
        acc[m][n] = __builtin_amdgcn_mfma_f32_16x16x32_bf16(af[m], bfr[n], acc[m][n], 0, 0, 0);
  }
  const int cr = (lane >> 4) * 4;
  const int cc = lane & 15;
  if (EPI == 2) {
#pragma unroll
    for (int n = 0; n < 4; ++n) {
      const int col = bn + wc + n * 16 + cc;
      const float bv = bias[col];
#pragma unroll
      for (int m = 0; m < 4; ++m) {
        const int rb = bm + wr + m * 16 + cr;
        bf4_t w;
#pragma unroll
        for (int r = 0; r < 4; ++r) w[r] = (__bf16)(acc[m][n][r] + bv);
        *(bf4_t*)(C + ((size_t)((rb >> 11) * 512 + col)) * 2048 + (rb & 2047)) = w;
      }
    }
    return;
  }
#pragma unroll
  for (int n = 0; n < 4; ++n) {
    const int col = bn + wc + n * 16 + cc;
    const float bv = bias[col];
#pragma unroll
    for (int m = 0; m < 4; ++m)
#pragma unroll
      for (int r = 0; r < 4; ++r) {
        const int row = bm + wr + m * 16 + cr + r;
        float v = acc[m][n][r] + bv;
        if (EPI == 1) v = 0.5f * v * (1.0f + erff(v * 0.70710678118f));
        C[(size_t)row * ldc + col] = (__bf16)v;
      }
  }
}

// ---------------- flash attention v2: zero-LDS, swapped QK^T, direct V^T reads.
// Block = 4 waves, each wave owns 32 queries. Grid = 512 flat blocks (XCD-remapped).
__global__ __launch_bounds__(256) void k_attn2(const __bf16* __restrict__ qb,
                                               const __bf16* __restrict__ kb,
                                               const __bf16* __restrict__ vt,
                                               const float* __restrict__ ocr_bias,
                                               __bf16* __restrict__ ctx) {
  const int t = threadIdx.x;
  const int lane = t & 63;
  const int wv = t >> 6;
  // XCD-friendly bijective remap: each XCD gets 4 (b,h) pairs entirely.
  const int i = blockIdx.x;  // 0..511
  const int xcd = i & 7;
  const int jj = i >> 3;
  const int bh = xcd + 8 * (jj & 3);
  const int xt = jj >> 2;  // 0..15
  const int b = bh >> 3, h = bh & 7;
  const int q0 = xt * 128 + wv * 32;
  const int fr = lane & 15;
  const int g = lane >> 4;
  const int fk = g * 8;
  const float sc = 0.125f;
  const float hb = ocr_bias[h];
  // Q B-fragments [tile][d-slice]
  bf8_t bq[2][2];
#pragma unroll
  for (int tt = 0; tt < 2; ++tt)
#pragma unroll
    for (int s = 0; s < 2; ++s)
      bq[tt][s] = *(const bf8_t*)(qb + ((size_t)b * S_ + q0 + tt * 16 + fr) * M_ + h * 64 + s * 32 + fk);
  const __bf16* kbase = kb + (size_t)b * S_ * M_ + h * 64;
  const __bf16* vbase = vt + ((size_t)(b * 512 + h * 64)) * (size_t)S_;
  float mreg[2] = {-1e30f, -1e30f};
  float lreg[2] = {0.f, 0.f};
  f4_t o[2][4];
#pragma unroll
  for (int tt = 0; tt < 2; ++tt)
#pragma unroll
    for (int d = 0; d < 4; ++d) o[tt][d] = (f4_t){0.f, 0.f, 0.f, 0.f};
  const int srcA = (fr + ((g & 1) << 5)) << 2;  // bpermute byte index
  const int srcB = srcA + 64;
  // prologue: K A-frags for chunk 0
  bf8_t akc[2][2];
#pragma unroll
  for (int hh = 0; hh < 2; ++hh)
#pragma unroll
    for (int s = 0; s < 2; ++s)
      akc[hh][s] = *(const bf8_t*)(kbase + (size_t)(hh * 16 + fr) * M_ + s * 32 + fk);

  for (int kv = 0; kv < S_; kv += 32) {
    // V^T B-frags for this chunk (used at the end -> latency hidden by softmax)
    bf8_t bv[4];
#pragma unroll
    for (int d = 0; d < 4; ++d)
      bv[d] = *(const bf8_t*)(vbase + (size_t)(d * 16 + fr) * S_ + kv + fk);
    // QK^T (S^T layout: row=k, col=q)
    f4_t st[2][2];
#pragma unroll
    for (int tt = 0; tt < 2; ++tt)
#pragma unroll
      for (int hh = 0; hh < 2; ++hh) {
        f4_t a = (f4_t){0.f, 0.f, 0.f, 0.f};
        a = __builtin_amdgcn_mfma_f32_16x16x32_bf16(akc[hh][0], bq[tt][0], a, 0, 0, 0);
        a = __builtin_amdgcn_mfma_f32_16x16x32_bf16(akc[hh][1], bq[tt][1], a, 0, 0, 0);
        st[tt][hh] = a;
      }
    // prefetch next chunk's K A-frags
    const int kvn = (kv + 32) & (S_ - 1);
    bf8_t akn[2][2];
#pragma unroll
    for (int hh = 0; hh < 2; ++hh)
#pragma unroll
      for (int s = 0; s < 2; ++s)
        akn[hh][s] = *(const bf8_t*)(kbase + (size_t)(kvn + hh * 16 + fr) * M_ + s * 32 + fk);
    // per-tile online softmax + PV
#pragma unroll
    for (int tt = 0; tt < 2; ++tt) {
      float p[2][4];
      float pm = -1e30f;
#pragma unroll
      for (int hh = 0; hh < 2; ++hh)
#pragma unroll
        for (int r = 0; r < 4; ++r) {
          p[hh][r] = st[tt][hh][r] * sc + hb;
          pm = fmaxf(pm, p[hh][r]);
        }
      pm = fmaxf(pm, __shfl_xor(pm, 16, 64));
      pm = fmaxf(pm, __shfl_xor(pm, 32, 64));
      const float mo = mreg[tt];
      const float mn = fmaxf(mo, pm);
      const float al = __expf(mo - mn);
      float ps = 0.f;
#pragma unroll
      for (int hh = 0; hh < 2; ++hh)
#pragma unroll
        for (int r = 0; r < 4; ++r) {
          p[hh][r] = __expf(p[hh][r] - mn);
          ps += p[hh][r];
        }
      ps += __shfl_xor(ps, 16, 64);
      ps += __shfl_xor(ps, 32, 64);
      lreg[tt] = lreg[tt] * al + ps;
      mreg[tt] = mn;
      // pack P^T pairs to bf16
      unsigned ch0 = packbf2(p[0][0], p[0][1]);
      unsigned ch1 = packbf2(p[0][2], p[0][3]);
      unsigned ch2 = packbf2(p[1][0], p[1][1]);
      unsigned ch3 = packbf2(p[1][2], p[1][3]);
      // assemble PV A-fragment via bpermute
      unsigned t0 = bperm(srcA, ch0), t2 = bperm(srcA, ch2);
      unsigned t1 = bperm(srcA, ch1), t3 = bperm(srcA, ch3);
      unsigned u0 = bperm(srcB, ch0), u2 = bperm(srcB, ch2);
      unsigned u1 = bperm(srcB, ch1), u3 = bperm(srcB, ch3);
      const bool lo = (g < 2);
      union { unsigned u[4]; bf8_t v; } aw;
      aw.u[0] = lo ? t0 : t2;
      aw.u[1] = lo ? t1 : t3;
      aw.u[2] = lo ? u0 : u2;
      aw.u[3] = lo ? u1 : u3;
      // rescale O rows and accumulate PV
      float alr[4];
#pragma unroll
      for (int r = 0; r < 4; ++r) alr[r] = __shfl(al, g * 4 + r, 64);
#pragma unroll
      for (int d = 0; d < 4; ++d) {
#pragma unroll
        for (int r = 0; r < 4; ++r) o[tt][d][r] *= alr[r];
        o[tt][d] = __builtin_amdgcn_mfma_f32_16x16x32_bf16(aw.v, bv[d], o[tt][d], 0, 0, 0);
      }
    }
#pragma unroll
    for (int hh = 0; hh < 2; ++hh)
#pragma unroll
      for (int s = 0; s < 2; ++s) akc[hh][s] = akn[hh][s];
  }
  // epilogue
#pragma unroll
  for (int tt = 0; tt < 2; ++tt) {
    float lrr[4];
#pragma unroll
    for (int r = 0; r < 4; ++r) lrr[r] = __shfl(lreg[tt], g * 4 + r, 64);
#pragma unroll
    for (int d = 0; d < 4; ++d)
#pragma unroll
      for (int r = 0; r < 4; ++r) {
        const float v = o[tt][d][r] / lrr[r];
        ctx[((size_t)b * S_ + q0 + tt * 16 + g * 4 + r) * M_ + h * 64 + d * 16 + fr] = (__bf16)v;
      }
  }
}

// ---------------- LayerNorm over D=1024, one block per row
__global__ __launch_bounds__(256) void k_ln(const __bf16* __restrict__ hh,
                                            const float* __restrict__ g,
                                            const float* __restrict__ bt,
                                            float* __restrict__ out) {
  const int row = blockIdx.x;
  const int t = threadIdx.x;
  const __bf16* hp = hh + (size_t)row * 1024 + t * 4;
  bf4_t v = *(const bf4_t*)hp;
  float f[4];
  float s1 = 0.f, s2 = 0.f;
#pragma unroll
  for (int j = 0; j < 4; ++j) {
    f[j] = (float)v[j];
    s1 += f[j];
    s2 += f[j] * f[j];
  }
#pragma unroll
  for (int d = 1; d < 64; d <<= 1) {
    s1 += __shfl_xor(s1, d, 64);
    s2 += __shfl_xor(s2, d, 64);
  }
  __shared__ float red[8];
  const int lane = t & 63, wv = t >> 6;
  if (lane == 0) { red[wv] = s1; red[4 + wv] = s2; }
  __syncthreads();
  const float S1 = red[0] + red[1] + red[2] + red[3];
  const float S2 = red[4] + red[5] + red[6] + red[7];
  const float mu = S1 * (1.f / 1024.f);
  const float var = S2 * (1.f / 1024.f) - mu * mu;
  const float inv = rsqrtf(var + 1e-5f);
  float* op = out + (size_t)row * 1024 + t * 4;
#pragma unroll
  for (int j = 0; j < 4; ++j) op[j] = (f[j] - mu) * inv * g[t * 4 + j] + bt[t * 4 + j];
}

extern "C" void kernel_launch(void* const* d_in, const int* in_sizes, int n_in,
                              void* d_out, int out_size, void* d_ws, size_t ws_size,
                              hipStream_t stream) {
  const float* x = (const float*)d_in[0];
  const float* W_enc = (const float*)d_in[1];
  const float* b_enc = (const float*)d_in[2];
  const float* Wq = (const float*)d_in[3];
  const float* bq = (const float*)d_in[4];
  const float* Wk = (const float*)d_in[5];
  const float* bk = (const float*)d_in[6];
  const float* Wv = (const float*)d_in[7];
  const float* bv = (const float*)d_in[8];
  const float* Wo = (const float*)d_in[9];
  const float* bo = (const float*)d_in[10];
  const float* ocr = (const float*)d_in[11];
  const float* W1 = (const float*)d_in[12];
  const float* b1 = (const float*)d_in[13];
  const float* W2 = (const float*)d_in[14];
  const float* b2 = (const float*)d_in[15];
  const float* lng = (const float*)d_in[16];
  const float* lnb = (const float*)d_in[17];
  float* out = (float*)d_out;

  __bf16* p = (__bf16*)d_ws;
  __bf16* ab = p;  p += (size_t)R_ * 1536;   // [x | attended] bf16, stride 1536
  __bf16* mem = p; p += (size_t)R_ * 512;
  __bf16* qb = p;  p += (size_t)R_ * 512;
  __bf16* kb = p;  p += (size_t)R_ * 512;
  __bf16* vtb = p; p += (size_t)R_ * 512;    // V^T: [b*512 + h*64 + d][s], ld = 2048
  __bf16* cx = p;  p += (size_t)R_ * 512;
  __bf16* h1 = p;  p += (size_t)R_ * 1024;
  __bf16* h2 = p;  p += (size_t)R_ * 1024;
  __bf16* WtE = p; p += (size_t)512 * 1024;
  __bf16* WtQ = p; p += (size_t)512 * 512;
  __bf16* WtK = p; p += (size_t)512 * 512;
  __bf16* WtV = p; p += (size_t)512 * 512;
  __bf16* WtO = p; p += (size_t)512 * 512;
  __bf16* Wt1 = p; p += (size_t)1024 * 1536;
  __bf16* Wt2 = p; p += (size_t)1024 * 1024;

  // 1) convert x -> ab[:, :1024]
  k_convert_x<<<4096, 256, 0, stream>>>(x, ab);
  // 2) transpose+convert all weights
  dim3 tb(32, 8);
  k_transpose<<<dim3(16, 32), tb, 0, stream>>>(W_enc, WtE, 1024, 512);
  k_transpose<<<dim3(16, 16), tb, 0, stream>>>(Wq, WtQ, 512, 512);
  k_transpose<<<dim3(16, 16), tb, 0, stream>>>(Wk, WtK, 512, 512);
  k_transpose<<<dim3(16, 16), tb, 0, stream>>>(Wv, WtV, 512, 512);
  k_transpose<<<dim3(16, 16), tb, 0, stream>>>(Wo, WtO, 512, 512);
  k_transpose<<<dim3(32, 48), tb, 0, stream>>>(W1, Wt1, 1536, 1024);
  k_transpose<<<dim3(32, 32), tb, 0, stream>>>(W2, Wt2, 1024, 1024);
  // 3) mem = x @ W_enc + b_enc
  k_gemm_bt<0><<<dim3(4, 64), 256, 0, stream>>>(ab, 1536, WtE, b_enc, mem, 512, 1024);
  // 4) q,k,v (v written transposed per batch)
  k_gemm_bt<0><<<dim3(4, 64), 256, 0, stream>>>(mem, 512, WtQ, bq, qb, 512, 512);
  k_gemm_bt<0><<<dim3(4, 64), 256, 0, stream>>>(mem, 512, WtK, bk, kb, 512, 512);
  k_gemm_bt<2><<<dim3(4, 64), 256, 0, stream>>>(mem, 512, WtV, bv, vtb, 2048, 512);
  // 5) attention -> cx
  k_attn2<<<512, 256, 0, stream>>>(qb, kb, vtb, ocr, cx);
  // 6) attended = cx @ Wo + bo  -> ab[:, 1024:1536]
  k_gemm_bt<0><<<dim3(4, 64), 256, 0, stream>>>(cx, 512, WtO, bo, ab + 1024, 1536, 512);
  // 7) h1 = gelu([x|att] @ W1 + b1)
  k_gemm_bt<1><<<dim3(8, 64), 256, 0, stream>>>(ab, 1536, Wt1, b1, h1, 1024, 1536);
  // 8) h2 = h1 @ W2 + b2
  k_gemm_bt<0><<<dim3(8, 64), 256, 0, stream>>>(h1, 1024, Wt2, b2, h2, 1024, 1024);
  // 9) layernorm -> out (fp32)
  k_ln<<<R_, 256, 0, stream>>>(h2, lng, lnb, out);
}

// Round 3
// 413.569 us; speedup vs baseline: 1.2984x; 1.0486x over previous
//
#include <hip/hip_runtime.h>
#include <math.h>

#define B_ 4
#define S_ 2048
#define D_ 1024
#define M_ 512
#define H_ 8
#define R_ (B_ * S_)  // 8192

typedef __bf16 bf8_t __attribute__((ext_vector_type(8)));
typedef __bf16 bf4_t __attribute__((ext_vector_type(4)));
typedef float f4_t __attribute__((ext_vector_type(4)));

typedef __attribute__((address_space(3))) void lds_void;
typedef const __attribute__((address_space(1))) void gl_void;
#define GL16(gp, lp) __builtin_amdgcn_global_load_lds((gl_void*)(gp), (lds_void*)(lp), 16, 0, 0)

__device__ inline unsigned packbf2(float a, float b) {
  union { __bf16 h[2]; unsigned u; } c;
  c.h[0] = (__bf16)a;
  c.h[1] = (__bf16)b;
  return c.u;
}
__device__ inline unsigned bperm(int srcBytes, unsigned v) {
  return (unsigned)__builtin_amdgcn_ds_bpermute(srcBytes, (int)v);
}

// ---------------- x (fp32) -> bf16, written into ab[:, 0:1024] with row stride 1536
__global__ __launch_bounds__(256) void k_convert_x(const float* __restrict__ x,
                                                   __bf16* __restrict__ ab) {
  size_t i = ((size_t)blockIdx.x * 256 + threadIdx.x) * 8;  // over R*1024
  size_t row = i >> 10;
  size_t col = i & 1023;
  f4_t f0 = *(const f4_t*)(x + i);
  f4_t f1 = *(const f4_t*)(x + i + 4);
  bf8_t v;
  v[0] = (__bf16)f0[0]; v[1] = (__bf16)f0[1]; v[2] = (__bf16)f0[2]; v[3] = (__bf16)f0[3];
  v[4] = (__bf16)f1[0]; v[5] = (__bf16)f1[1]; v[6] = (__bf16)f1[2]; v[7] = (__bf16)f1[3];
  *(bf8_t*)(ab + row * 1536 + col) = v;
}

// ---------------- W[K][N] fp32 -> Wt[N][K] bf16 (tiled transpose)
__global__ void k_transpose(const float* __restrict__ in, __bf16* __restrict__ out,
                            int K, int N) {
  __shared__ float tile[32][33];
  const int n0 = blockIdx.x * 32;
  const int k0 = blockIdx.y * 32;
  const int tx = threadIdx.x;  // 0..31
  const int ty = threadIdx.y;  // 0..7
#pragma unroll
  for (int j = 0; j < 32; j += 8)
    tile[ty + j][tx] = in[(size_t)(k0 + ty + j) * N + n0 + tx];
  __syncthreads();
#pragma unroll
  for (int j = 0; j < 32; j += 8)
    out[(size_t)(n0 + ty + j) * K + k0 + tx] = (__bf16)tile[tx][ty + j];
}

// ---------------- GEMM: C[m][n] = sum_k A[m][k] * Bt[n][k] + bias[n]
// EPI 0: plain bf16 store. EPI 1: exact GELU.
// Tiles 128x128, BK=32, 4 waves. m97 structure: global_load_lds width-16.
template <int EPI>
__global__ __launch_bounds__(256) void k_gemm_bt(const __bf16* __restrict__ A, int lda,
                                                 const __bf16* __restrict__ Bt,
                                                 const float* __restrict__ bias,
                                                 __bf16* __restrict__ C, int ldc, int K) {
  __shared__ __bf16 As[128 * 32];
  __shared__ __bf16 Bs[128 * 32];
  const int t = threadIdx.x;
  const int lane = t & 63;
  const int wv = t >> 6;
  const int wr = (wv >> 1) * 64;
  const int wc = (wv & 1) * 64;
  const int bm = blockIdx.y * 128;
  const int bn = blockIdx.x * 128;
  const int c0 = wv * 2, c1 = wv * 2 + 1;
  const int sr0 = c0 * 16 + (lane >> 2);
  const int sr1 = c1 * 16 + (lane >> 2);
  const int scol = (lane & 3) * 8;
  const __bf16* Ag0 = A + (size_t)(bm + sr0) * lda + scol;
  const __bf16* Ag1 = A + (size_t)(bm + sr1) * lda + scol;
  const __bf16* Bg0 = Bt + (size_t)(bn + sr0) * (size_t)K + scol;
  const __bf16* Bg1 = Bt + (size_t)(bn + sr1) * (size_t)K + scol;
  __bf16* Al0 = As + c0 * 512;
  __bf16* Al1 = As + c1 * 512;
  __bf16* Bl0 = Bs + c0 * 512;
  __bf16* Bl1 = Bs + c1 * 512;
  f4_t acc[4][4];
#pragma unroll
  for (int m = 0; m < 4; ++m)
#pragma unroll
    for (int n = 0; n < 4; ++n) acc[m][n] = (f4_t){0.f, 0.f, 0.f, 0.f};
  const int fr = lane & 15;
  const int fk = (lane >> 4) * 8;
  for (int k0 = 0; k0 < K; k0 += 32) {
    __syncthreads();
    GL16(Ag0 + k0, Al0);
    GL16(Ag1 + k0, Al1);
    GL16(Bg0 + k0, Bl0);
    GL16(Bg1 + k0, Bl1);
    __syncthreads();
    bf8_t af[4], bfr[4];
#pragma unroll
    for (int m = 0; m < 4; ++m) af[m] = *(const bf8_t*)&As[(wr + m * 16 + fr) * 32 + fk];
#pragma unroll
    for (int n = 0; n < 4; ++n) bfr[n] = *(const bf8_t*)&Bs[(wc + n * 16 + fr) * 32 + fk];
#pragma unroll
    for (int m = 0; m < 4; ++m)
#pragma unroll
      for (int n = 0; n < 4; ++n)
        acc[m][n] = __builtin_amdgcn_mfma_f32_16x16x32_bf16(af[m], bfr[n], acc[m][n], 0, 0, 0);
  }
  const int cr = (lane >> 4) * 4;
  const int cc = lane & 15;
#pragma unroll
  for (int n = 0; n < 4; ++n) {
    const int col = bn + wc + n * 16 + cc;
    const float bv = bias[col];
#pragma unroll
    for (int m = 0; m < 4; ++m)
#pragma unroll
      for (int r = 0; r < 4; ++r) {
        const int row = bm + wr + m * 16 + cr + r;
        float v = acc[m][n][r] + bv;
        if (EPI == 1) v = 0.5f * v * (1.0f + erff(v * 0.70710678118f));
        C[(size_t)row * ldc + col] = (__bf16)v;
      }
  }
}

// ---------------- fused QKV GEMM: A=mem[8192x512], Bt=[WtQ;WtK;WtV] (1536x512).
// cols 0-511 -> qb, 512-1023 -> kb, 1024-1535 -> vtb transposed per batch.
__global__ __launch_bounds__(256) void k_gemm_qkv(const __bf16* __restrict__ A,
                                                  const __bf16* __restrict__ Bt,
                                                  const float* __restrict__ bq,
                                                  const float* __restrict__ bk,
                                                  const float* __restrict__ bv,
                                                  __bf16* __restrict__ qb,
                                                  __bf16* __restrict__ kb,
                                                  __bf16* __restrict__ vtb) {
  const int K = 512;
  __shared__ __bf16 As[128 * 32];
  __shared__ __bf16 Bs[128 * 32];
  const int t = threadIdx.x;
  const int lane = t & 63;
  const int wv = t >> 6;
  const int wr = (wv >> 1) * 64;
  const int wc = (wv & 1) * 64;
  const int bm = blockIdx.y * 128;
  const int bn = blockIdx.x * 128;
  const int c0 = wv * 2, c1 = wv * 2 + 1;
  const int sr0 = c0 * 16 + (lane >> 2);
  const int sr1 = c1 * 16 + (lane >> 2);
  const int scol = (lane & 3) * 8;
  const __bf16* Ag0 = A + (size_t)(bm + sr0) * K + scol;
  const __bf16* Ag1 = A + (size_t)(bm + sr1) * K + scol;
  const __bf16* Bg0 = Bt + (size_t)(bn + sr0) * (size_t)K + scol;
  const __bf16* Bg1 = Bt + (size_t)(bn + sr1) * (size_t)K + scol;
  __bf16* Al0 = As + c0 * 512;
  __bf16* Al1 = As + c1 * 512;
  __bf16* Bl0 = Bs + c0 * 512;
  __bf16* Bl1 = Bs + c1 * 512;
  f4_t acc[4][4];
#pragma unroll
  for (int m = 0; m < 4; ++m)
#pragma unroll
    for (int n = 0; n < 4; ++n) acc[m][n] = (f4_t){0.f, 0.f, 0.f, 0.f};
  const int fr = lane & 15;
  const int fk = (lane >> 4) * 8;
  for (int k0 = 0; k0 < K; k0 += 32) {
    __syncthreads();
    GL16(Ag0 + k0, Al0);
    GL16(Ag1 + k0, Al1);
    GL16(Bg0 + k0, Bl0);
    GL16(Bg1 + k0, Bl1);
    __syncthreads();
    bf8_t af[4], bfr[4];
#pragma unroll
    for (int m = 0; m < 4; ++m) af[m] = *(const bf8_t*)&As[(wr + m * 16 + fr) * 32 + fk];
#pragma unroll
    for (int n = 0; n < 4; ++n) bfr[n] = *(const bf8_t*)&Bs[(wc + n * 16 + fr) * 32 + fk];
#pragma unroll
    for (int m = 0; m < 4; ++m)
#pragma unroll
      for (int n = 0; n < 4; ++n)
        acc[m][n] = __builtin_amdgcn_mfma_f32_16x16x32_bf16(af[m], bfr[n], acc[m][n], 0, 0, 0);
  }
  const int cr = (lane >> 4) * 4;
  const int cc = lane & 15;
  const int seg = bn >> 9;  // 0=q, 1=k, 2=v (block never straddles)
  const float* bsel = (seg == 0) ? bq : (seg == 1) ? bk : bv;
  if (seg < 2) {
    __bf16* dst = (seg == 0) ? qb : kb;
#pragma unroll
    for (int n = 0; n < 4; ++n) {
      const int col = (bn + wc + n * 16 + cc) & 511;
      const float bvv = bsel[col];
#pragma unroll
      for (int m = 0; m < 4; ++m)
#pragma unroll
        for (int r = 0; r < 4; ++r) {
          const int row = bm + wr + m * 16 + cr + r;
          dst[(size_t)row * 512 + col] = (__bf16)(acc[m][n][r] + bvv);
        }
    }
  } else {
#pragma unroll
    for (int n = 0; n < 4; ++n) {
      const int col = (bn + wc + n * 16 + cc) & 511;
      const float bvv = bsel[col];
#pragma unroll
      for (int m = 0; m < 4; ++m) {
        const int rb = bm + wr + m * 16 + cr;
        bf4_t w;
#pragma unroll
        for (int r = 0; r < 4; ++r) w[r] = (__bf16)(acc[m][n][r] + bvv);
        *(bf4_t*)(vtb + ((size_t)((rb >> 11) * 512 + col)) * 2048 + (rb & 2047)) = w;
      }
    }
  }
}

// ---------------- flash attention v3: zero-LDS, swapped QK^T, KVBLK=64,
// exp2-domain softmax (Q pre-scaled), defer-max, setprio, ping-pong K prefetch.
// ocr_bias dropped: per-head scalar added to every score cancels in softmax.
__global__ __launch_bounds__(256, 2) void k_attn3(const __bf16* __restrict__ qb,
                                                  const __bf16* __restrict__ kb,
                                                  const __bf16* __restrict__ vt,
                                                  __bf16* __restrict__ ctx) {
  const int t = threadIdx.x;
  const int lane = t & 63;
  const int wv = t >> 6;
  const int i = blockIdx.x;  // 0..511, XCD-bijective remap
  const int xcd = i & 7;
  const int jj = i >> 3;
  const int bh = xcd + 8 * (jj & 3);
  const int xt = jj >> 2;  // 0..15
  const int b = bh >> 3, h = bh & 7;
  const int q0 = xt * 128 + wv * 32;
  const int fr = lane & 15;
  const int g = lane >> 4;
  const int fk = g * 8;
  const float qs = 0.125f * 1.44269504f;  // 1/sqrt(64) * log2(e)
  // Q B-fragments, pre-scaled
  bf8_t bqf[2][2];
#pragma unroll
  for (int tt = 0; tt < 2; ++tt)
#pragma unroll
    for (int s = 0; s < 2; ++s) {
      bf8_t raw = *(const bf8_t*)(qb + ((size_t)b * S_ + q0 + tt * 16 + fr) * M_ + h * 64 + s * 32 + fk);
      bf8_t sc;
#pragma unroll
      for (int e = 0; e < 8; ++e) sc[e] = (__bf16)((float)raw[e] * qs);
      bqf[tt][s] = sc;
    }
  const __bf16* kbase = kb + (size_t)b * S_ * M_ + h * 64;
  const __bf16* vbase = vt + ((size_t)(b * 512 + h * 64)) * (size_t)S_;
  float mreg[2] = {-3e38f, -3e38f};
  float lreg[2] = {0.f, 0.f};
  f4_t o[2][4];
#pragma unroll
  for (int tt = 0; tt < 2; ++tt)
#pragma unroll
    for (int d = 0; d < 4; ++d) o[tt][d] = (f4_t){0.f, 0.f, 0.f, 0.f};
  const int srcA = (fr + ((g & 1) << 5)) << 2;
  const int srcB = srcA + 64;
  // prologue: K chunk 0 (64 keys = 4 subtiles x 2 d-slices)
  bf8_t ak0[4][2], ak1[4][2];
#pragma unroll
  for (int hh = 0; hh < 4; ++hh)
#pragma unroll
    for (int s = 0; s < 2; ++s)
      ak0[hh][s] = *(const bf8_t*)(kbase + (size_t)(hh * 16 + fr) * M_ + s * 32 + fk);

#define ATTN_CHUNK(AKC, AKN, KV)                                                          \
  {                                                                                       \
    bf8_t bvf[2][4];                                                                      \
    _Pragma("unroll") for (int ks = 0; ks < 2; ++ks)                                      \
        _Pragma("unroll") for (int d = 0; d < 4; ++d)                                     \
            bvf[ks][d] = *(const bf8_t*)(vbase + (size_t)(d * 16 + fr) * S_ + (KV) + ks * 32 + fk); \
    f4_t st[2][4];                                                                        \
    __builtin_amdgcn_s_setprio(1);                                                        \
    _Pragma("unroll") for (int tt = 0; tt < 2; ++tt)                                      \
        _Pragma("unroll") for (int hh = 0; hh < 4; ++hh) {                                \
      f4_t a = (f4_t){0.f, 0.f, 0.f, 0.f};                                                \
      a = __builtin_amdgcn_mfma_f32_16x16x32_bf16(AKC[hh][0], bqf[tt][0], a, 0, 0, 0);    \
      a = __builtin_amdgcn_mfma_f32_16x16x32_bf16(AKC[hh][1], bqf[tt][1], a, 0, 0, 0);    \
      st[tt][hh] = a;                                                                     \
    }                                                                                     \
    __builtin_amdgcn_s_setprio(0);                                                        \
    const int kvn = ((KV) + 64) & (S_ - 1);                                               \
    _Pragma("unroll") for (int hh = 0; hh < 4; ++hh)                                      \
        _Pragma("unroll") for (int s = 0; s < 2; ++s)                                     \
            AKN[hh][s] = *(const bf8_t*)(kbase + (size_t)(kvn + hh * 16 + fr) * M_ + s * 32 + fk); \
    _Pragma("unroll") for (int tt = 0; tt < 2; ++tt) {                                    \
      float pm = -3e38f;                                                                  \
      _Pragma("unroll") for (int hh = 0; hh < 4; ++hh)                                    \
          _Pragma("unroll") for (int r = 0; r < 4; ++r) pm = fmaxf(pm, st[tt][hh][r]);    \
      pm = fmaxf(pm, __shfl_xor(pm, 16, 64));                                             \
      pm = fmaxf(pm, __shfl_xor(pm, 32, 64));                                             \
      float mo = mreg[tt];                                                                \
      if (!__all(pm <= mo + 8.f)) {                                                       \
        const float mn = fmaxf(mo, pm);                                                   \
        const float al = exp2f(mo - mn);                                                  \
        mreg[tt] = mn;                                                                    \
        mo = mn;                                                                          \
        lreg[tt] *= al;                                                                   \
        float alr[4];                                                                     \
        _Pragma("unroll") for (int r = 0; r < 4; ++r) alr[r] = __shfl(al, g * 4 + r, 64); \
        _Pragma("unroll") for (int d = 0; d < 4; ++d)                                     \
            _Pragma("unroll") for (int r = 0; r < 4; ++r) o[tt][d][r] *= alr[r];          \
      }                                                                                   \
      float p[4][4];                                                                      \
      float ps = 0.f;                                                                     \
      _Pragma("unroll") for (int hh = 0; hh < 4; ++hh)                                    \
          _Pragma("unroll") for (int r = 0; r < 4; ++r) {                                 \
        p[hh][r] = exp2f(st[tt][hh][r] - mo);                                             \
        ps += p[hh][r];                                                                   \
      }                                                                                   \
      ps += __shfl_xor(ps, 16, 64);                                                       \
      ps += __shfl_xor(ps, 32, 64);                                                       \
      lreg[tt] += ps;                                                                     \
      union { unsigned u[4]; bf8_t v; } aw[2];                                            \
      _Pragma("unroll") for (int ks = 0; ks < 2; ++ks) {                                  \
        unsigned ch0 = packbf2(p[2 * ks][0], p[2 * ks][1]);                               \
        unsigned ch1 = packbf2(p[2 * ks][2], p[2 * ks][3]);                               \
        unsigned ch2 = packbf2(p[2 * ks + 1][0], p[2 * ks + 1][1]);                       \
        unsigned ch3 = packbf2(p[2 * ks + 1][2], p[2 * ks + 1][3]);                       \
        unsigned t0 = bperm(srcA, ch0), t2 = bperm(srcA, ch2);                            \
        unsigned t1 = bperm(srcA, ch1), t3 = bperm(srcA, ch3);                            \
        unsigned u0 = bperm(srcB, ch0), u2 = bperm(srcB, ch2);                            \
        unsigned u1 = bperm(srcB, ch1), u3 = bperm(srcB, ch3);                            \
        const bool lo = (g < 2);                                                          \
        aw[ks].u[0] = lo ? t0 : t2;                                                       \
        aw[ks].u[1] = lo ? t1 : t3;                                                       \
        aw[ks].u[2] = lo ? u0 : u2;                                                       \
        aw[ks].u[3] = lo ? u1 : u3;                                                       \
      }                                                                                   \
      __builtin_amdgcn_s_setprio(1);                                                      \
      _Pragma("unroll") for (int d = 0; d < 4; ++d) {                                     \
        o[tt][d] = __builtin_amdgcn_mfma_f32_16x16x32_bf16(aw[0].v, bvf[0][d], o[tt][d], 0, 0, 0); \
        o[tt][d] = __builtin_amdgcn_mfma_f32_16x16x32_bf16(aw[1].v, bvf[1][d], o[tt][d], 0, 0, 0); \
      }                                                                                   \
      __builtin_amdgcn_s_setprio(0);                                                      \
    }                                                                                     \
  }

  for (int kv = 0; kv < S_; kv += 128) {
    ATTN_CHUNK(ak0, ak1, kv);
    ATTN_CHUNK(ak1, ak0, kv + 64);
  }
#undef ATTN_CHUNK

  // epilogue: divide by row sums, write ctx
#pragma unroll
  for (int tt = 0; tt < 2; ++tt) {
    float lrr[4];
#pragma unroll
    for (int r = 0; r < 4; ++r) lrr[r] = __shfl(lreg[tt], g * 4 + r, 64);
#pragma unroll
    for (int d = 0; d < 4; ++d)
#pragma unroll
      for (int r = 0; r < 4; ++r) {
        const float v = o[tt][d][r] / lrr[r];
        ctx[((size_t)b * S_ + q0 + tt * 16 + g * 4 + r) * M_ + h * 64 + d * 16 + fr] = (__bf16)v;
      }
  }
}

// ---------------- LayerNorm over D=1024, one block per row
__global__ __launch_bounds__(256) void k_ln(const __bf16* __restrict__ hh,
                                            const float* __restrict__ g,
                                            const float* __restrict__ bt,
                                            float* __restrict__ out) {
  const int row = blockIdx.x;
  const int t = threadIdx.x;
  const __bf16* hp = hh + (size_t)row * 1024 + t * 4;
  bf4_t v = *(const bf4_t*)hp;
  float f[4];
  float s1 = 0.f, s2 = 0.f;
#pragma unroll
  for (int j = 0; j < 4; ++j) {
    f[j] = (float)v[j];
    s1 += f[j];
    s2 += f[j] * f[j];
  }
#pragma unroll
  for (int d = 1; d < 64; d <<= 1) {
    s1 += __shfl_xor(s1, d, 64);
    s2 += __shfl_xor(s2, d, 64);
  }
  __shared__ float red[8];
  const int lane = t & 63, wv = t >> 6;
  if (lane == 0) { red[wv] = s1; red[4 + wv] = s2; }
  __syncthreads();
  const float S1 = red[0] + red[1] + red[2] + red[3];
  const float S2 = red[4] + red[5] + red[6] + red[7];
  const float mu = S1 * (1.f / 1024.f);
  const float var = S2 * (1.f / 1024.f) - mu * mu;
  const float inv = rsqrtf(var + 1e-5f);
  float* op = out + (size_t)row * 1024 + t * 4;
#pragma unroll
  for (int j = 0; j < 4; ++j) op[j] = (f[j] - mu) * inv * g[t * 4 + j] + bt[t * 4 + j];
}

extern "C" void kernel_launch(void* const* d_in, const int* in_sizes, int n_in,
                              void* d_out, int out_size, void* d_ws, size_t ws_size,
                              hipStream_t stream) {
  const float* x = (const float*)d_in[0];
  const float* W_enc = (const float*)d_in[1];
  const float* b_enc = (const float*)d_in[2];
  const float* Wq = (const float*)d_in[3];
  const float* bq = (const float*)d_in[4];
  const float* Wk = (const float*)d_in[5];
  const float* bk = (const float*)d_in[6];
  const float* Wv = (const float*)d_in[7];
  const float* bv = (const float*)d_in[8];
  const float* Wo = (const float*)d_in[9];
  const float* bo = (const float*)d_in[10];
  const float* W1 = (const float*)d_in[12];
  const float* b1 = (const float*)d_in[13];
  const float* W2 = (const float*)d_in[14];
  const float* b2 = (const float*)d_in[15];
  const float* lng = (const float*)d_in[16];
  const float* lnb = (const float*)d_in[17];
  float* out = (float*)d_out;

  __bf16* p = (__bf16*)d_ws;
  __bf16* ab = p;  p += (size_t)R_ * 1536;   // [x | attended] bf16, stride 1536
  __bf16* mem = p; p += (size_t)R_ * 512;
  __bf16* qb = p;  p += (size_t)R_ * 512;
  __bf16* kb = p;  p += (size_t)R_ * 512;
  __bf16* vtb = p; p += (size_t)R_ * 512;    // V^T: [b*512 + h*64 + d][s], ld = 2048
  __bf16* cx = p;  p += (size_t)R_ * 512;
  __bf16* h1 = p;  p += (size_t)R_ * 1024;
  __bf16* h2 = p;  p += (size_t)R_ * 1024;
  __bf16* WtE = p; p += (size_t)512 * 1024;
  __bf16* WtQ = p; p += (size_t)512 * 512;   // WtQ/WtK/WtV contiguous => fused B
  __bf16* WtK = p; p += (size_t)512 * 512;
  __bf16* WtV = p; p += (size_t)512 * 512;
  __bf16* WtO = p; p += (size_t)512 * 512;
  __bf16* Wt1 = p; p += (size_t)1024 * 1536;
  __bf16* Wt2 = p; p += (size_t)1024 * 1024;

  // 1) convert x -> ab[:, :1024]
  k_convert_x<<<4096, 256, 0, stream>>>(x, ab);
  // 2) transpose+convert all weights
  dim3 tb(32, 8);
  k_transpose<<<dim3(16, 32), tb, 0, stream>>>(W_enc, WtE, 1024, 512);
  k_transpose<<<dim3(16, 16), tb, 0, stream>>>(Wq, WtQ, 512, 512);
  k_transpose<<<dim3(16, 16), tb, 0, stream>>>(Wk, WtK, 512, 512);
  k_transpose<<<dim3(16, 16), tb, 0, stream>>>(Wv, WtV, 512, 512);
  k_transpose<<<dim3(16, 16), tb, 0, stream>>>(Wo, WtO, 512, 512);
  k_transpose<<<dim3(32, 48), tb, 0, stream>>>(W1, Wt1, 1536, 1024);
  k_transpose<<<dim3(32, 32), tb, 0, stream>>>(W2, Wt2, 1024, 1024);
  // 3) mem = x @ W_enc + b_enc
  k_gemm_bt<0><<<dim3(4, 64), 256, 0, stream>>>(ab, 1536, WtE, b_enc, mem, 512, 1024);
  // 4) fused q,k,v (v written transposed per batch)
  k_gemm_qkv<<<dim3(12, 64), 256, 0, stream>>>(mem, WtQ, bq, bk, bv, qb, kb, vtb);
  // 5) attention -> cx
  k_attn3<<<512, 256, 0, stream>>>(qb, kb, vtb, cx);
  // 6) attended = cx @ Wo + bo  -> ab[:, 1024:1536]
  k_gemm_bt<0><<<dim3(4, 64), 256, 0, stream>>>(cx, 512, WtO, bo, ab + 1024, 1536, 512);
  // 7) h1 = gelu([x|att] @ W1 + b1)
  k_gemm_bt<1><<<dim3(8, 64), 256, 0, stream>>>(ab, 1536, Wt1, b1, h1, 1024, 1536);
  // 8) h2 = h1 @ W2 + b2
  k_gemm_bt<0><<<dim3(8, 64), 256, 0, stream>>>(h1, 1024, Wt2, b2, h2, 1024, 1024);
  // 9) layernorm -> out (fp32)
  k_ln<<<R_, 256, 0, stream>>>(h2, lng, lnb, out);
}

// Round 4
// 370.125 us; speedup vs baseline: 1.4508x; 1.1174x over previous
//
#include <hip/hip_runtime.h>
#include <math.h>

#define B_ 4
#define S_ 2048
#define D_ 1024
#define M_ 512
#define H_ 8
#define R_ (B_ * S_)  // 8192

typedef __bf16 bf8_t __attribute__((ext_vector_type(8)));
typedef __bf16 bf4_t __attribute__((ext_vector_type(4)));
typedef float f4_t __attribute__((ext_vector_type(4)));

typedef __attribute__((address_space(3))) void lds_void;
typedef const __attribute__((address_space(1))) void gl_void;
#define GL16(gp, lp) __builtin_amdgcn_global_load_lds((gl_void*)(gp), (lds_void*)(lp), 16, 0, 0)

__device__ inline unsigned packbf2(float a, float b) {
  union { __bf16 h[2]; unsigned u; } c;
  c.h[0] = (__bf16)a;
  c.h[1] = (__bf16)b;
  return c.u;
}
__device__ inline unsigned bperm(int srcBytes, unsigned v) {
  return (unsigned)__builtin_amdgcn_ds_bpermute(srcBytes, (int)v);
}

// ---------------- merged prep: 7 weight transposes (fp32->bf16 W^T) + x convert.
// blocks [0, start[7]) = transposes; [start[7], start[7]+4096) = x->ab convert.
struct PrepArgs {
  const float* src[7];
  __bf16* dst[7];
  int K[7], N[7];
  int start[8];
  const float* x;
  __bf16* ab;
};

__global__ __launch_bounds__(256) void k_prep(PrepArgs a) {
  const int t = threadIdx.x;
  const int id = blockIdx.x;
  if (id < a.start[7]) {
    int w = 0;
    while (id >= a.start[w + 1]) ++w;
    const int local = id - a.start[w];
    const int bxw = a.N[w] >> 5;
    const int n0 = (local % bxw) * 32;
    const int k0 = (local / bxw) * 32;
    const int tx = t & 31, ty = t >> 5;
    __shared__ float tile[32][33];
    const float* in = a.src[w];
    __bf16* out = a.dst[w];
    const int N = a.N[w], K = a.K[w];
#pragma unroll
    for (int j = 0; j < 32; j += 8)
      tile[ty + j][tx] = in[(size_t)(k0 + ty + j) * N + n0 + tx];
    __syncthreads();
#pragma unroll
    for (int j = 0; j < 32; j += 8)
      out[(size_t)(n0 + ty + j) * K + k0 + tx] = (__bf16)tile[tx][ty + j];
  } else {
    size_t i = (((size_t)(id - a.start[7])) * 256 + t) * 8;  // over R*1024
    size_t row = i >> 10;
    size_t col = i & 1023;
    f4_t f0 = *(const f4_t*)(a.x + i);
    f4_t f1 = *(const f4_t*)(a.x + i + 4);
    bf8_t v;
    v[0] = (__bf16)f0[0]; v[1] = (__bf16)f0[1]; v[2] = (__bf16)f0[2]; v[3] = (__bf16)f0[3];
    v[4] = (__bf16)f1[0]; v[5] = (__bf16)f1[1]; v[6] = (__bf16)f1[2]; v[7] = (__bf16)f1[3];
    *(bf8_t*)(a.ab + row * 1536 + col) = v;
  }
}

// ---------------- GEMM: C[m][n] = sum_k A[m][k] * Bt[n][k] + bias[n]
// EPI 0: plain bf16 store. EPI 1: exact GELU.
template <int EPI>
__global__ __launch_bounds__(256) void k_gemm_bt(const __bf16* __restrict__ A, int lda,
                                                 const __bf16* __restrict__ Bt,
                                                 const float* __restrict__ bias,
                                                 __bf16* __restrict__ C, int ldc, int K) {
  __shared__ __bf16 As[128 * 32];
  __shared__ __bf16 Bs[128 * 32];
  const int t = threadIdx.x;
  const int lane = t & 63;
  const int wv = t >> 6;
  const int wr = (wv >> 1) * 64;
  const int wc = (wv & 1) * 64;
  const int bm = blockIdx.y * 128;
  const int bn = blockIdx.x * 128;
  const int c0 = wv * 2, c1 = wv * 2 + 1;
  const int sr0 = c0 * 16 + (lane >> 2);
  const int sr1 = c1 * 16 + (lane >> 2);
  const int scol = (lane & 3) * 8;
  const __bf16* Ag0 = A + (size_t)(bm + sr0) * lda + scol;
  const __bf16* Ag1 = A + (size_t)(bm + sr1) * lda + scol;
  const __bf16* Bg0 = Bt + (size_t)(bn + sr0) * (size_t)K + scol;
  const __bf16* Bg1 = Bt + (size_t)(bn + sr1) * (size_t)K + scol;
  __bf16* Al0 = As + c0 * 512;
  __bf16* Al1 = As + c1 * 512;
  __bf16* Bl0 = Bs + c0 * 512;
  __bf16* Bl1 = Bs + c1 * 512;
  f4_t acc[4][4];
#pragma unroll
  for (int m = 0; m < 4; ++m)
#pragma unroll
    for (int n = 0; n < 4; ++n) acc[m][n] = (f4_t){0.f, 0.f, 0.f, 0.f};
  const int fr = lane & 15;
  const int fk = (lane >> 4) * 8;
  for (int k0 = 0; k0 < K; k0 += 32) {
    __syncthreads();
    GL16(Ag0 + k0, Al0);
    GL16(Ag1 + k0, Al1);
    GL16(Bg0 + k0, Bl0);
    GL16(Bg1 + k0, Bl1);
    __syncthreads();
    bf8_t af[4], bfr[4];
#pragma unroll
    for (int m = 0; m < 4; ++m) af[m] = *(const bf8_t*)&As[(wr + m * 16 + fr) * 32 + fk];
#pragma unroll
    for (int n = 0; n < 4; ++n) bfr[n] = *(const bf8_t*)&Bs[(wc + n * 16 + fr) * 32 + fk];
#pragma unroll
    for (int m = 0; m < 4; ++m)
#pragma unroll
      for (int n = 0; n < 4; ++n)
        acc[m][n] = __builtin_amdgcn_mfma_f32_16x16x32_bf16(af[m], bfr[n], acc[m][n], 0, 0, 0);
  }
  const int cr = (lane >> 4) * 4;
  const int cc = lane & 15;
#pragma unroll
  for (int n = 0; n < 4; ++n) {
    const int col = bn + wc + n * 16 + cc;
    const float bv = bias[col];
#pragma unroll
    for (int m = 0; m < 4; ++m)
#pragma unroll
      for (int r = 0; r < 4; ++r) {
        const int row = bm + wr + m * 16 + cr + r;
        float v = acc[m][n][r] + bv;
        if (EPI == 1) v = 0.5f * v * (1.0f + erff(v * 0.70710678118f));
        C[(size_t)row * ldc + col] = (__bf16)v;
      }
  }
}

// ---------------- fused QKV GEMM: A=mem[8192x512], Bt=[WtQ;WtK;WtV] (1536x512).
// cols 0-511 -> qb row-major; 512-1023 -> packed-K fragments; 1024-1535 -> packed-V^T.
// Packed-K: elem (((bh*128 + k16)*2 + s)*512 + l*8 + e) = K[key=k16*16+(l&15)][d=s*32+(l>>4)*8+e]
// Packed-V: elem ((((bh*32 + kc)*2 + ks)*4 + d16)*512 + l*8 + e)
//            = V[key=kc*64+ks*32+(l>>4)*8+e][d=d16*16+(l&15)]
__global__ __launch_bounds__(256) void k_gemm_qkv(const __bf16* __restrict__ A,
                                                  const __bf16* __restrict__ Bt,
                                                  const float* __restrict__ bq,
                                                  const float* __restrict__ bk,
                                                  const float* __restrict__ bvb,
                                                  __bf16* __restrict__ qb,
                                                  __bf16* __restrict__ pkd,
                                                  __bf16* __restrict__ pvd) {
  const int K = 512;
  __shared__ __bf16 As[128 * 32];
  __shared__ __bf16 Bs[128 * 32];
  const int t = threadIdx.x;
  const int lane = t & 63;
  const int wv = t >> 6;
  const int wr = (wv >> 1) * 64;
  const int wc = (wv & 1) * 64;
  const int bm = blockIdx.y * 128;
  const int bn = blockIdx.x * 128;
  const int c0 = wv * 2, c1 = wv * 2 + 1;
  const int sr0 = c0 * 16 + (lane >> 2);
  const int sr1 = c1 * 16 + (lane >> 2);
  const int scol = (lane & 3) * 8;
  const __bf16* Ag0 = A + (size_t)(bm + sr0) * K + scol;
  const __bf16* Ag1 = A + (size_t)(bm + sr1) * K + scol;
  const __bf16* Bg0 = Bt + (size_t)(bn + sr0) * (size_t)K + scol;
  const __bf16* Bg1 = Bt + (size_t)(bn + sr1) * (size_t)K + scol;
  __bf16* Al0 = As + c0 * 512;
  __bf16* Al1 = As + c1 * 512;
  __bf16* Bl0 = Bs + c0 * 512;
  __bf16* Bl1 = Bs + c1 * 512;
  f4_t acc[4][4];
#pragma unroll
  for (int m = 0; m < 4; ++m)
#pragma unroll
    for (int n = 0; n < 4; ++n) acc[m][n] = (f4_t){0.f, 0.f, 0.f, 0.f};
  const int fr = lane & 15;
  const int fk = (lane >> 4) * 8;
  for (int k0 = 0; k0 < K; k0 += 32) {
    __syncthreads();
    GL16(Ag0 + k0, Al0);
    GL16(Ag1 + k0, Al1);
    GL16(Bg0 + k0, Bl0);
    GL16(Bg1 + k0, Bl1);
    __syncthreads();
    bf8_t af[4], bfr[4];
#pragma unroll
    for (int m = 0; m < 4; ++m) af[m] = *(const bf8_t*)&As[(wr + m * 16 + fr) * 32 + fk];
#pragma unroll
    for (int n = 0; n < 4; ++n) bfr[n] = *(const bf8_t*)&Bs[(wc + n * 16 + fr) * 32 + fk];
#pragma unroll
    for (int m = 0; m < 4; ++m)
#pragma unroll
      for (int n = 0; n < 4; ++n)
        acc[m][n] = __builtin_amdgcn_mfma_f32_16x16x32_bf16(af[m], bfr[n], acc[m][n], 0, 0, 0);
  }
  const int cr = (lane >> 4) * 4;
  const int cc = lane & 15;
  const int seg = bn >> 9;  // 0=q, 1=k, 2=v (blocks never straddle segments)
  const int b0 = bm >> 11;  // batch (128 | 2048)
  if (seg == 0) {
#pragma unroll
    for (int n = 0; n < 4; ++n) {
      const int col = (bn + wc + n * 16 + cc) & 511;
      const float bvv = bq[col];
#pragma unroll
      for (int m = 0; m < 4; ++m)
#pragma unroll
        for (int r = 0; r < 4; ++r) {
          const int row = bm + wr + m * 16 + cr + r;
          qb[(size_t)row * 512 + col] = (__bf16)(acc[m][n][r] + bvv);
        }
    }
  } else if (seg == 1) {
#pragma unroll
    for (int n = 0; n < 4; ++n) {
      const int col = (bn + wc + n * 16 + cc) & 511;
      const int hh = col >> 6, d = col & 63;
      const int s = d >> 5, g2 = (d >> 3) & 3, e = d & 7;
      const float bvv = bk[col];
#pragma unroll
      for (int m = 0; m < 4; ++m)
#pragma unroll
        for (int r = 0; r < 4; ++r) {
          const int key = (bm + wr + m * 16 + cr + r) & 2047;
          const int k16 = key >> 4, frk = key & 15;
          pkd[(((size_t)(b0 * 8 + hh) * 128 + k16) * 2 + s) * 512 + (g2 * 16 + frk) * 8 + e] =
              (__bf16)(acc[m][n][r] + bvv);
        }
    }
  } else {
#pragma unroll
    for (int n = 0; n < 4; ++n) {
      const int col = (bn + wc + n * 16 + cc) & 511;
      const int hh = col >> 6, dd = col & 63;
      const int d16 = dd >> 4, fv = dd & 15;
      const float bvv = bvb[col];
#pragma unroll
      for (int m = 0; m < 4; ++m) {
        const int keyb = (bm + wr + m * 16 + cr) & 2047;
        const int kc = keyb >> 6, ks = (keyb >> 5) & 1, g2 = (keyb >> 3) & 3, e0 = keyb & 7;
        bf4_t w;
#pragma unroll
        for (int r = 0; r < 4; ++r) w[r] = (__bf16)(acc[m][n][r] + bvv);
        *(bf4_t*)&pvd[((((size_t)(b0 * 8 + hh) * 32 + kc) * 2 + ks) * 4 + d16) * 512 +
                      (g2 * 16 + fv) * 8 + e0] = w;
      }
    }
  }
}

// ---------------- flash attention v4: packed K/V staged through LDS (m97-style),
// lane-linear ds_read_b128 fragments, swapped QK^T, exp2 softmax, defer-max, setprio.
__global__ __launch_bounds__(256, 2) void k_attn4(const __bf16* __restrict__ qb,
                                                  const __bf16* __restrict__ pk,
                                                  const __bf16* __restrict__ pv,
                                                  __bf16* __restrict__ ctx) {
  __shared__ __bf16 KL[8192];  // 16KB: 16 fragment packets of 512 elems (128 keys)
  __shared__ __bf16 VL[8192];
  const int t = threadIdx.x;
  const int lane = t & 63;
  const int wv = t >> 6;
  const int i = blockIdx.x;  // 0..511, XCD-bijective remap
  const int xcd = i & 7;
  const int jj = i >> 3;
  const int bh = xcd + 8 * (jj & 3);
  const int xt = jj >> 2;  // 0..15
  const int b = bh >> 3, h = bh & 7;
  const int q0 = xt * 128 + wv * 32;
  const int fr = lane & 15;
  const int g = lane >> 4;
  const int fk = g * 8;
  const float qs = 0.125f * 1.44269504f;  // 1/sqrt(64) * log2(e)
  // Q B-fragments, pre-scaled (one-time 16-row gather)
  bf8_t bqf[2][2];
#pragma unroll
  for (int tt = 0; tt < 2; ++tt)
#pragma unroll
    for (int s = 0; s < 2; ++s) {
      bf8_t raw = *(const bf8_t*)(qb + ((size_t)b * S_ + q0 + tt * 16 + fr) * M_ + h * 64 + s * 32 + fk);
      bf8_t sc;
#pragma unroll
      for (int e = 0; e < 8; ++e) sc[e] = (__bf16)((float)raw[e] * qs);
      bqf[tt][s] = sc;
    }
  const __bf16* pkc = pk + (size_t)bh * 131072;
  const __bf16* pvc = pv + (size_t)bh * 131072;
  float mreg[2] = {-3e38f, -3e38f};
  float lreg[2] = {0.f, 0.f};
  f4_t o[2][4];
#pragma unroll
  for (int tt = 0; tt < 2; ++tt)
#pragma unroll
    for (int d = 0; d < 4; ++d) o[tt][d] = (f4_t){0.f, 0.f, 0.f, 0.f};
  const int srcA = (fr + ((g & 1) << 5)) << 2;
  const int srcB = srcA + 64;

#define STAGE(KV)                                                                      \
  {                                                                                    \
    const size_t goff = (size_t)(KV) * 64;                                             \
    _Pragma("unroll") for (int j = 0; j < 4; ++j) {                                    \
      GL16(pkc + goff + (wv * 4 + j) * 512 + lane * 8, KL + (wv * 4 + j) * 512);       \
      GL16(pvc + goff + (wv * 4 + j) * 512 + lane * 8, VL + (wv * 4 + j) * 512);       \
    }                                                                                  \
  }

#define COMPUTE64(HALF)                                                                   \
  {                                                                                       \
    bf8_t ak[4][2], bvf[2][4];                                                            \
    _Pragma("unroll") for (int hh = 0; hh < 4; ++hh)                                      \
        _Pragma("unroll") for (int s = 0; s < 2; ++s)                                     \
            ak[hh][s] = *(const bf8_t*)&KL[(HALF) * 4096 + (hh * 2 + s) * 512 + lane * 8];\
    _Pragma("unroll") for (int ks = 0; ks < 2; ++ks)                                      \
        _Pragma("unroll") for (int d = 0; d < 4; ++d)                                     \
            bvf[ks][d] = *(const bf8_t*)&VL[(HALF) * 4096 + (ks * 4 + d) * 512 + lane * 8];\
    f4_t st[2][4];                                                                        \
    __builtin_amdgcn_s_setprio(1);                                                        \
    _Pragma("unroll") for (int tt = 0; tt < 2; ++tt)                                      \
        _Pragma("unroll") for (int hh = 0; hh < 4; ++hh) {                                \
      f4_t a = (f4_t){0.f, 0.f, 0.f, 0.f};                                                \
      a = __builtin_amdgcn_mfma_f32_16x16x32_bf16(ak[hh][0], bqf[tt][0], a, 0, 0, 0);     \
      a = __builtin_amdgcn_mfma_f32_16x16x32_bf16(ak[hh][1], bqf[tt][1], a, 0, 0, 0);     \
      st[tt][hh] = a;                                                                     \
    }                                                                                     \
    __builtin_amdgcn_s_setprio(0);                                                        \
    _Pragma("unroll") for (int tt = 0; tt < 2; ++tt) {                                    \
      float pm = -3e38f;                                                                  \
      _Pragma("unroll") for (int hh = 0; hh < 4; ++hh)                                    \
          _Pragma("unroll") for (int r = 0; r < 4; ++r) pm = fmaxf(pm, st[tt][hh][r]);    \
      pm = fmaxf(pm, __shfl_xor(pm, 16, 64));                                             \
      pm = fmaxf(pm, __shfl_xor(pm, 32, 64));                                             \
      float mo = mreg[tt];                                                                \
      if (!__all(pm <= mo + 8.f)) {                                                       \
        const float mn = fmaxf(mo, pm);                                                   \
        const float al = exp2f(mo - mn);                                                  \
        mreg[tt] = mn;                                                                    \
        mo = mn;                                                                          \
        lreg[tt] *= al;                                                                   \
        float alr[4];                                                                     \
        _Pragma("unroll") for (int r = 0; r < 4; ++r) alr[r] = __shfl(al, g * 4 + r, 64); \
        _Pragma("unroll") for (int d = 0; d < 4; ++d)                                     \
            _Pragma("unroll") for (int r = 0; r < 4; ++r) o[tt][d][r] *= alr[r];          \
      }                                                                                   \
      float p[4][4];                                                                      \
      float ps = 0.f;                                                                     \
      _Pragma("unroll") for (int hh = 0; hh < 4; ++hh)                                    \
          _Pragma("unroll") for (int r = 0; r < 4; ++r) {                                 \
        p[hh][r] = exp2f(st[tt][hh][r] - mo);                                             \
        ps += p[hh][r];                                                                   \
      }                                                                                   \
      ps += __shfl_xor(ps, 16, 64);                                                       \
      ps += __shfl_xor(ps, 32, 64);                                                       \
      lreg[tt] += ps;                                                                     \
      union { unsigned u[4]; bf8_t v; } aw[2];                                            \
      _Pragma("unroll") for (int ks = 0; ks < 2; ++ks) {                                  \
        unsigned ch0 = packbf2(p[2 * ks][0], p[2 * ks][1]);                               \
        unsigned ch1 = packbf2(p[2 * ks][2], p[2 * ks][3]);                               \
        unsigned ch2 = packbf2(p[2 * ks + 1][0], p[2 * ks + 1][1]);                       \
        unsigned ch3 = packbf2(p[2 * ks + 1][2], p[2 * ks + 1][3]);                       \
        unsigned t0 = bperm(srcA, ch0), t2 = bperm(srcA, ch2);                            \
        unsigned t1 = bperm(srcA, ch1), t3 = bperm(srcA, ch3);                            \
        unsigned u0 = bperm(srcB, ch0), u2 = bperm(srcB, ch2);                            \
        unsigned u1 = bperm(srcB, ch1), u3 = bperm(srcB, ch3);                            \
        const bool lo = (g < 2);                                                          \
        aw[ks].u[0] = lo ? t0 : t2;                                                       \
        aw[ks].u[1] = lo ? t1 : t3;                                                       \
        aw[ks].u[2] = lo ? u0 : u2;                                                       \
        aw[ks].u[3] = lo ? u1 : u3;                                                       \
      }                                                                                   \
      __builtin_amdgcn_s_setprio(1);                                                      \
      _Pragma("unroll") for (int d = 0; d < 4; ++d) {                                     \
        o[tt][d] = __builtin_amdgcn_mfma_f32_16x16x32_bf16(aw[0].v, bvf[0][d], o[tt][d], 0, 0, 0); \
        o[tt][d] = __builtin_amdgcn_mfma_f32_16x16x32_bf16(aw[1].v, bvf[1][d], o[tt][d], 0, 0, 0); \
      }                                                                                   \
      __builtin_amdgcn_s_setprio(0);                                                      \
    }                                                                                     \
  }

  STAGE(0);
  for (int kv = 0; kv < S_; kv += 128) {
    __syncthreads();  // staging of chunk kv complete (compiler drains vmcnt)
    COMPUTE64(0);
    COMPUTE64(1);
    __syncthreads();  // all waves done reading LDS
    if (kv + 128 < S_) STAGE(kv + 128);
  }
#undef STAGE
#undef COMPUTE64

  // epilogue: divide by row sums, write ctx
#pragma unroll
  for (int tt = 0; tt < 2; ++tt) {
    float lrr[4];
#pragma unroll
    for (int r = 0; r < 4; ++r) lrr[r] = __shfl(lreg[tt], g * 4 + r, 64);
#pragma unroll
    for (int d = 0; d < 4; ++d)
#pragma unroll
      for (int r = 0; r < 4; ++r) {
        const float v = o[tt][d][r] / lrr[r];
        ctx[((size_t)b * S_ + q0 + tt * 16 + g * 4 + r) * M_ + h * 64 + d * 16 + fr] = (__bf16)v;
      }
  }
}

// ---------------- LayerNorm over D=1024, one block per row
__global__ __launch_bounds__(256) void k_ln(const __bf16* __restrict__ hh,
                                            const float* __restrict__ g,
                                            const float* __restrict__ bt,
                                            float* __restrict__ out) {
  const int row = blockIdx.x;
  const int t = threadIdx.x;
  const __bf16* hp = hh + (size_t)row * 1024 + t * 4;
  bf4_t v = *(const bf4_t*)hp;
  float f[4];
  float s1 = 0.f, s2 = 0.f;
#pragma unroll
  for (int j = 0; j < 4; ++j) {
    f[j] = (float)v[j];
    s1 += f[j];
    s2 += f[j] * f[j];
  }
#pragma unroll
  for (int d = 1; d < 64; d <<= 1) {
    s1 += __shfl_xor(s1, d, 64);
    s2 += __shfl_xor(s2, d, 64);
  }
  __shared__ float red[8];
  const int lane = t & 63, wv = t >> 6;
  if (lane == 0) { red[wv] = s1; red[4 + wv] = s2; }
  __syncthreads();
  const float S1 = red[0] + red[1] + red[2] + red[3];
  const float S2 = red[4] + red[5] + red[6] + red[7];
  const float mu = S1 * (1.f / 1024.f);
  const float var = S2 * (1.f / 1024.f) - mu * mu;
  const float inv = rsqrtf(var + 1e-5f);
  float* op = out + (size_t)row * 1024 + t * 4;
#pragma unroll
  for (int j = 0; j < 4; ++j) op[j] = (f[j] - mu) * inv * g[t * 4 + j] + bt[t * 4 + j];
}

extern "C" void kernel_launch(void* const* d_in, const int* in_sizes, int n_in,
                              void* d_out, int out_size, void* d_ws, size_t ws_size,
                              hipStream_t stream) {
  const float* x = (const float*)d_in[0];
  const float* W_enc = (const float*)d_in[1];
  const float* b_enc = (const float*)d_in[2];
  const float* Wq = (const float*)d_in[3];
  const float* bq = (const float*)d_in[4];
  const float* Wk = (const float*)d_in[5];
  const float* bk = (const float*)d_in[6];
  const float* Wv = (const float*)d_in[7];
  const float* bv = (const float*)d_in[8];
  const float* Wo = (const float*)d_in[9];
  const float* bo = (const float*)d_in[10];
  const float* W1 = (const float*)d_in[12];
  const float* b1 = (const float*)d_in[13];
  const float* W2 = (const float*)d_in[14];
  const float* b2 = (const float*)d_in[15];
  const float* lng = (const float*)d_in[16];
  const float* lnb = (const float*)d_in[17];
  float* out = (float*)d_out;

  __bf16* p = (__bf16*)d_ws;
  __bf16* ab = p;  p += (size_t)R_ * 1536;   // [x | attended] bf16, stride 1536
  __bf16* mem = p; p += (size_t)R_ * 512;
  __bf16* qb = p;  p += (size_t)R_ * 512;
  __bf16* pk = p;  p += (size_t)R_ * 512;    // packed-K fragments
  __bf16* pv = p;  p += (size_t)R_ * 512;    // packed-V^T fragments
  __bf16* cx = p;  p += (size_t)R_ * 512;
  __bf16* h1 = p;  p += (size_t)R_ * 1024;
  __bf16* h2 = p;  p += (size_t)R_ * 1024;
  __bf16* WtE = p; p += (size_t)512 * 1024;
  __bf16* WtQ = p; p += (size_t)512 * 512;   // WtQ/WtK/WtV contiguous => fused B
  __bf16* WtK = p; p += (size_t)512 * 512;
  __bf16* WtV = p; p += (size_t)512 * 512;
  __bf16* WtO = p; p += (size_t)512 * 512;
  __bf16* Wt1 = p; p += (size_t)1024 * 1536;
  __bf16* Wt2 = p; p += (size_t)1024 * 1024;

  // 1) merged prep: all weight transposes + x convert (one launch)
  PrepArgs pa;
  pa.src[0] = W_enc; pa.dst[0] = WtE; pa.K[0] = 1024; pa.N[0] = 512;
  pa.src[1] = Wq;    pa.dst[1] = WtQ; pa.K[1] = 512;  pa.N[1] = 512;
  pa.src[2] = Wk;    pa.dst[2] = WtK; pa.K[2] = 512;  pa.N[2] = 512;
  pa.src[3] = Wv;    pa.dst[3] = WtV; pa.K[3] = 512;  pa.N[3] = 512;
  pa.src[4] = Wo;    pa.dst[4] = WtO; pa.K[4] = 512;  pa.N[4] = 512;
  pa.src[5] = W1;    pa.dst[5] = Wt1; pa.K[5] = 1536; pa.N[5] = 1024;
  pa.src[6] = W2;    pa.dst[6] = Wt2; pa.K[6] = 1024; pa.N[6] = 1024;
  int acc0 = 0;
  for (int w = 0; w < 7; ++w) {
    pa.start[w] = acc0;
    acc0 += (pa.N[w] >> 5) * (pa.K[w] >> 5);
  }
  pa.start[7] = acc0;  // 4096
  pa.x = x; pa.ab = ab;
  k_prep<<<acc0 + 4096, 256, 0, stream>>>(pa);
  // 2) mem = x @ W_enc + b_enc
  k_gemm_bt<0><<<dim3(4, 64), 256, 0, stream>>>(ab, 1536, WtE, b_enc, mem, 512, 1024);
  // 3) fused q,k,v (k,v written fragment-packed)
  k_gemm_qkv<<<dim3(12, 64), 256, 0, stream>>>(mem, WtQ, bq, bk, bv, qb, pk, pv);
  // 4) attention -> cx
  k_attn4<<<512, 256, 0, stream>>>(qb, pk, pv, cx);
  // 5) attended = cx @ Wo + bo  -> ab[:, 1024:1536]
  k_gemm_bt<0><<<dim3(4, 64), 256, 0, stream>>>(cx, 512, WtO, bo, ab + 1024, 1536, 512);
  // 6) h1 = gelu([x|att] @ W1 + b1)
  k_gemm_bt<1><<<dim3(8, 64), 256, 0, stream>>>(ab, 1536, Wt1, b1, h1, 1024, 1536);
  // 7) h2 = h1 @ W2 + b2
  k_gemm_bt<0><<<dim3(8, 64), 256, 0, stream>>>(h1, 1024, Wt2, b2, h2, 1024, 1024);
  // 8) layernorm -> out (fp32)
  k_ln<<<R_, 256, 0, stream>>>(h2, lng, lnb, out);
}

// Round 5
// 360.430 us; speedup vs baseline: 1.4899x; 1.0269x over previous
//
#include <hip/hip_runtime.h>
#include <math.h>

#define B_ 4
#define S_ 2048
#define D_ 1024
#define M_ 512
#define H_ 8
#define R_ (B_ * S_)  // 8192

typedef __bf16 bf8_t __attribute__((ext_vector_type(8)));
typedef __bf16 bf4_t __attribute__((ext_vector_type(4)));
typedef float f4_t __attribute__((ext_vector_type(4)));

typedef __attribute__((address_space(3))) void lds_void;
typedef const __attribute__((address_space(1))) void gl_void;
#define GL16(gp, lp) __builtin_amdgcn_global_load_lds((gl_void*)(gp), (lds_void*)(lp), 16, 0, 0)

__device__ inline unsigned packbf2(float a, float b) {
  union { __bf16 h[2]; unsigned u; } c;
  c.h[0] = (__bf16)a;
  c.h[1] = (__bf16)b;
  return c.u;
}
__device__ inline unsigned bperm(int srcBytes, unsigned v) {
  return (unsigned)__builtin_amdgcn_ds_bpermute(srcBytes, (int)v);
}

// ---------------- merged prep: 7 weight transposes (fp32->bf16 W^T) + x convert.
struct PrepArgs {
  const float* src[7];
  __bf16* dst[7];
  int K[7], N[7];
  int start[8];
  const float* x;
  __bf16* ab;
};

__global__ __launch_bounds__(256) void k_prep(PrepArgs a) {
  const int t = threadIdx.x;
  const int id = blockIdx.x;
  if (id < a.start[7]) {
    int w = 0;
    while (id >= a.start[w + 1]) ++w;
    const int local = id - a.start[w];
    const int bxw = a.N[w] >> 5;
    const int n0 = (local % bxw) * 32;
    const int k0 = (local / bxw) * 32;
    const int tx = t & 31, ty = t >> 5;
    __shared__ float tile[32][33];
    const float* in = a.src[w];
    __bf16* out = a.dst[w];
    const int N = a.N[w], K = a.K[w];
#pragma unroll
    for (int j = 0; j < 32; j += 8)
      tile[ty + j][tx] = in[(size_t)(k0 + ty + j) * N + n0 + tx];
    __syncthreads();
#pragma unroll
    for (int j = 0; j < 32; j += 8)
      out[(size_t)(n0 + ty + j) * K + k0 + tx] = (__bf16)tile[tx][ty + j];
  } else {
    size_t i = (((size_t)(id - a.start[7])) * 256 + t) * 8;  // over R*1024
    size_t row = i >> 10;
    size_t col = i & 1023;
    f4_t f0 = *(const f4_t*)(a.x + i);
    f4_t f1 = *(const f4_t*)(a.x + i + 4);
    bf8_t v;
    v[0] = (__bf16)f0[0]; v[1] = (__bf16)f0[1]; v[2] = (__bf16)f0[2]; v[3] = (__bf16)f0[3];
    v[4] = (__bf16)f1[0]; v[5] = (__bf16)f1[1]; v[6] = (__bf16)f1[2]; v[7] = (__bf16)f1[3];
    *(bf8_t*)(a.ab + row * 1536 + col) = v;
  }
}

// ---------------- GEMM v2: double-buffered LDS, ONE barrier per K-step (T3-min).
// C[m][n] = sum_k A[m][k]*Bt[n][k] + bias[n]. BM in {64,128}, BN=128, BK=32, 4 waves.
// EPI 0: plain store. EPI 1: exact GELU.
template <int BM, int EPI>
__global__ __launch_bounds__(256) void k_gemm2(const __bf16* __restrict__ A, int lda,
                                               const __bf16* __restrict__ Bt,
                                               const float* __restrict__ bias,
                                               __bf16* __restrict__ C, int ldc, int K) {
  constexpr int ACH = BM / 16;  // A staging chunks (1KB each)
  constexpr int MR = BM / 32;   // m-frags per wave
  __shared__ __bf16 As[2][BM * 32];
  __shared__ __bf16 Bs[2][128 * 32];
  const int t = threadIdx.x;
  const int lane = t & 63;
  const int wv = t >> 6;
  const int wr = (wv >> 1) * (BM / 2);
  const int wc = (wv & 1) * 64;
  const int bm = blockIdx.y * BM;
  const int bn = blockIdx.x * 128;
  const int srow = lane >> 2;
  const int scol = (lane & 3) * 8;
  f4_t acc[MR][4];
#pragma unroll
  for (int m = 0; m < MR; ++m)
#pragma unroll
    for (int n = 0; n < 4; ++n) acc[m][n] = (f4_t){0.f, 0.f, 0.f, 0.f};
  const int fr = lane & 15;
  const int fk = (lane >> 4) * 8;
  const int NT = K >> 5;

#define STAGE_G(k0, buf)                                                                   \
  {                                                                                        \
    _Pragma("unroll") for (int c = wv; c < ACH; c += 4)                                    \
        GL16(A + (size_t)(bm + c * 16 + srow) * lda + (k0) + scol, &As[buf][c * 512]);     \
    _Pragma("unroll") for (int c = wv; c < 8; c += 4)                                      \
        GL16(Bt + (size_t)(bn + c * 16 + srow) * (size_t)K + (k0) + scol, &Bs[buf][c * 512]); \
  }

  STAGE_G(0, 0);
  __syncthreads();
  for (int it = 0; it < NT; ++it) {
    const int cur = it & 1;
    if (it + 1 < NT) STAGE_G((it + 1) << 5, cur ^ 1);
    bf8_t af[MR], bfr[4];
#pragma unroll
    for (int m = 0; m < MR; ++m) af[m] = *(const bf8_t*)&As[cur][(wr + m * 16 + fr) * 32 + fk];
#pragma unroll
    for (int n = 0; n < 4; ++n) bfr[n] = *(const bf8_t*)&Bs[cur][(wc + n * 16 + fr) * 32 + fk];
    __builtin_amdgcn_s_setprio(1);
#pragma unroll
    for (int m = 0; m < MR; ++m)
#pragma unroll
      for (int n = 0; n < 4; ++n)
        acc[m][n] = __builtin_amdgcn_mfma_f32_16x16x32_bf16(af[m], bfr[n], acc[m][n], 0, 0, 0);
    __builtin_amdgcn_s_setprio(0);
    __syncthreads();
  }
#undef STAGE_G

  const int cr = (lane >> 4) * 4;
  const int cc = lane & 15;
#pragma unroll
  for (int n = 0; n < 4; ++n) {
    const int col = bn + wc + n * 16 + cc;
    const float bv = bias[col];
#pragma unroll
    for (int m = 0; m < MR; ++m)
#pragma unroll
      for (int r = 0; r < 4; ++r) {
        const int row = bm + wr + m * 16 + cr + r;
        float v = acc[m][n][r] + bv;
        if (EPI == 1) v = 0.5f * v * (1.0f + erff(v * 0.70710678118f));
        C[(size_t)row * ldc + col] = (__bf16)v;
      }
  }
}

// ---------------- fused QKV GEMM (dbuf): A=mem[8192x512], Bt=[WtQ;WtK;WtV].
// cols 0-511 -> qb row-major; 512-1023 -> packed-K fragments; 1024-1535 -> packed-V^T.
__global__ __launch_bounds__(256) void k_gemm_qkv(const __bf16* __restrict__ A,
                                                  const __bf16* __restrict__ Bt,
                                                  const float* __restrict__ bq,
                                                  const float* __restrict__ bk,
                                                  const float* __restrict__ bvb,
                                                  __bf16* __restrict__ qb,
                                                  __bf16* __restrict__ pkd,
                                                  __bf16* __restrict__ pvd) {
  const int K = 512;
  __shared__ __bf16 As[2][128 * 32];
  __shared__ __bf16 Bs[2][128 * 32];
  const int t = threadIdx.x;
  const int lane = t & 63;
  const int wv = t >> 6;
  const int wr = (wv >> 1) * 64;
  const int wc = (wv & 1) * 64;
  const int bm = blockIdx.y * 128;
  const int bn = blockIdx.x * 128;
  const int srow = lane >> 2;
  const int scol = (lane & 3) * 8;
  f4_t acc[4][4];
#pragma unroll
  for (int m = 0; m < 4; ++m)
#pragma unroll
    for (int n = 0; n < 4; ++n) acc[m][n] = (f4_t){0.f, 0.f, 0.f, 0.f};
  const int fr = lane & 15;
  const int fk = (lane >> 4) * 8;

#define STAGE_Q(k0, buf)                                                                   \
  {                                                                                        \
    _Pragma("unroll") for (int c = wv; c < 8; c += 4) {                                    \
      GL16(A + (size_t)(bm + c * 16 + srow) * K + (k0) + scol, &As[buf][c * 512]);         \
      GL16(Bt + (size_t)(bn + c * 16 + srow) * (size_t)K + (k0) + scol, &Bs[buf][c * 512]); \
    }                                                                                      \
  }

  STAGE_Q(0, 0);
  __syncthreads();
  for (int it = 0; it < 16; ++it) {
    const int cur = it & 1;
    if (it + 1 < 16) STAGE_Q((it + 1) << 5, cur ^ 1);
    bf8_t af[4], bfr[4];
#pragma unroll
    for (int m = 0; m < 4; ++m) af[m] = *(const bf8_t*)&As[cur][(wr + m * 16 + fr) * 32 + fk];
#pragma unroll
    for (int n = 0; n < 4; ++n) bfr[n] = *(const bf8_t*)&Bs[cur][(wc + n * 16 + fr) * 32 + fk];
    __builtin_amdgcn_s_setprio(1);
#pragma unroll
    for (int m = 0; m < 4; ++m)
#pragma unroll
      for (int n = 0; n < 4; ++n)
        acc[m][n] = __builtin_amdgcn_mfma_f32_16x16x32_bf16(af[m], bfr[n], acc[m][n], 0, 0, 0);
    __builtin_amdgcn_s_setprio(0);
    __syncthreads();
  }
#undef STAGE_Q

  const int cr = (lane >> 4) * 4;
  const int cc = lane & 15;
  const int seg = bn >> 9;  // 0=q, 1=k, 2=v
  const int b0 = bm >> 11;  // batch
  if (seg == 0) {
#pragma unroll
    for (int n = 0; n < 4; ++n) {
      const int col = (bn + wc + n * 16 + cc) & 511;
      const float bvv = bq[col];
#pragma unroll
      for (int m = 0; m < 4; ++m)
#pragma unroll
        for (int r = 0; r < 4; ++r) {
          const int row = bm + wr + m * 16 + cr + r;
          qb[(size_t)row * 512 + col] = (__bf16)(acc[m][n][r] + bvv);
        }
    }
  } else if (seg == 1) {
#pragma unroll
    for (int n = 0; n < 4; ++n) {
      const int col = (bn + wc + n * 16 + cc) & 511;
      const int hh = col >> 6, d = col & 63;
      const int s = d >> 5, g2 = (d >> 3) & 3, e = d & 7;
      const float bvv = bk[col];
#pragma unroll
      for (int m = 0; m < 4; ++m)
#pragma unroll
        for (int r = 0; r < 4; ++r) {
          const int key = (bm + wr + m * 16 + cr + r) & 2047;
          const int k16 = key >> 4, frk = key & 15;
          pkd[(((size_t)(b0 * 8 + hh) * 128 + k16) * 2 + s) * 512 + (g2 * 16 + frk) * 8 + e] =
              (__bf16)(acc[m][n][r] + bvv);
        }
    }
  } else {
#pragma unroll
    for (int n = 0; n < 4; ++n) {
      const int col = (bn + wc + n * 16 + cc) & 511;
      const int hh = col >> 6, dd = col & 63;
      const int d16 = dd >> 4, fv = dd & 15;
      const float bvv = bvb[col];
#pragma unroll
      for (int m = 0; m < 4; ++m) {
        const int keyb = (bm + wr + m * 16 + cr) & 2047;
        const int kc = keyb >> 6, ks = (keyb >> 5) & 1, g2 = (keyb >> 3) & 3, e0 = keyb & 7;
        bf4_t w;
#pragma unroll
        for (int r = 0; r < 4; ++r) w[r] = (__bf16)(acc[m][n][r] + bvv);
        *(bf4_t*)&pvd[((((size_t)(b0 * 8 + hh) * 32 + kc) * 2 + ks) * 4 + d16) * 512 +
                      (g2 * 16 + fv) * 8 + e0] = w;
      }
    }
  }
}

// ---------------- flash attention v5: Q-split (1024 blocks, 16 q/wave),
// 64-key chunks double-buffered in LDS, one barrier per chunk, 4 blocks/CU.
__global__ __launch_bounds__(256, 4) void k_attn5(const __bf16* __restrict__ qb,
                                                  const __bf16* __restrict__ pk,
                                                  const __bf16* __restrict__ pv,
                                                  __bf16* __restrict__ ctx) {
  __shared__ __bf16 KL[2][4096];  // 8KB per buffer = 64 keys
  __shared__ __bf16 VL[2][4096];
  const int t = threadIdx.x;
  const int lane = t & 63;
  const int wv = t >> 6;
  const int i = blockIdx.x;  // 0..1023, XCD-bijective remap
  const int xcd = i & 7;
  const int jj = i >> 3;       // 0..127
  const int bh = xcd + 8 * (jj & 3);
  const int qt = jj >> 2;      // 0..31
  const int b = bh >> 3, h = bh & 7;
  const int q0 = qt * 64 + wv * 16;
  const int fr = lane & 15;
  const int g = lane >> 4;
  const int fk = g * 8;
  const float qs = 0.125f * 1.44269504f;  // 1/sqrt(64) * log2(e)
  // Q B-fragments (2 k-slices), pre-scaled
  bf8_t bqf[2];
#pragma unroll
  for (int s = 0; s < 2; ++s) {
    bf8_t raw = *(const bf8_t*)(qb + ((size_t)b * S_ + q0 + fr) * M_ + h * 64 + s * 32 + fk);
    bf8_t sc;
#pragma unroll
    for (int e = 0; e < 8; ++e) sc[e] = (__bf16)((float)raw[e] * qs);
    bqf[s] = sc;
  }
  const __bf16* pkc = pk + (size_t)bh * 131072;
  const __bf16* pvc = pv + (size_t)bh * 131072;
  float mreg = -3e38f, lreg = 0.f;
  f4_t o[4];
#pragma unroll
  for (int d = 0; d < 4; ++d) o[d] = (f4_t){0.f, 0.f, 0.f, 0.f};
  const int srcA = (fr + ((g & 1) << 5)) << 2;
  const int srcB = srcA + 64;

#define STAGEA(c, buf)                                                      \
  {                                                                         \
    const __bf16* kg = pkc + (size_t)(c) * 4096;                            \
    const __bf16* vg = pvc + (size_t)(c) * 4096;                            \
    GL16(kg + (wv * 2 + 0) * 512 + lane * 8, &KL[buf][(wv * 2 + 0) * 512]); \
    GL16(kg + (wv * 2 + 1) * 512 + lane * 8, &KL[buf][(wv * 2 + 1) * 512]); \
    GL16(vg + (wv * 2 + 0) * 512 + lane * 8, &VL[buf][(wv * 2 + 0) * 512]); \
    GL16(vg + (wv * 2 + 1) * 512 + lane * 8, &VL[buf][(wv * 2 + 1) * 512]); \
  }

  STAGEA(0, 0);
  __syncthreads();
  for (int c = 0; c < 32; ++c) {
    const int cur = c & 1;
    if (c + 1 < 32) STAGEA(c + 1, cur ^ 1);
    // fragment reads (lane-linear, conflict-free)
    bf8_t ak[4][2], bvf[2][4];
#pragma unroll
    for (int hh = 0; hh < 4; ++hh)
#pragma unroll
      for (int s = 0; s < 2; ++s)
        ak[hh][s] = *(const bf8_t*)&KL[cur][(hh * 2 + s) * 512 + lane * 8];
#pragma unroll
    for (int ks = 0; ks < 2; ++ks)
#pragma unroll
      for (int d = 0; d < 4; ++d)
        bvf[ks][d] = *(const bf8_t*)&VL[cur][(ks * 4 + d) * 512 + lane * 8];
    // QK^T (8 MFMA): st[hh] row=key(g*4+r), col=query(fr)
    f4_t st[4];
    __builtin_amdgcn_s_setprio(1);
#pragma unroll
    for (int hh = 0; hh < 4; ++hh) {
      f4_t a = (f4_t){0.f, 0.f, 0.f, 0.f};
      a = __builtin_amdgcn_mfma_f32_16x16x32_bf16(ak[hh][0], bqf[0], a, 0, 0, 0);
      a = __builtin_amdgcn_mfma_f32_16x16x32_bf16(ak[hh][1], bqf[1], a, 0, 0, 0);
      st[hh] = a;
    }
    __builtin_amdgcn_s_setprio(0);
    // online softmax (exp2 domain) + defer-max
    float pm = -3e38f;
#pragma unroll
    for (int hh = 0; hh < 4; ++hh)
#pragma unroll
      for (int r = 0; r < 4; ++r) pm = fmaxf(pm, st[hh][r]);
    pm = fmaxf(pm, __shfl_xor(pm, 16, 64));
    pm = fmaxf(pm, __shfl_xor(pm, 32, 64));
    float mo = mreg;
    if (!__all(pm <= mo + 8.f)) {
      const float mn = fmaxf(mo, pm);
      const float al = exp2f(mo - mn);
      mreg = mn;
      mo = mn;
      lreg *= al;
      float alr[4];
#pragma unroll
      for (int r = 0; r < 4; ++r) alr[r] = __shfl(al, g * 4 + r, 64);
#pragma unroll
      for (int d = 0; d < 4; ++d)
#pragma unroll
        for (int r = 0; r < 4; ++r) o[d][r] *= alr[r];
    }
    float p[4][4];
    float ps = 0.f;
#pragma unroll
    for (int hh = 0; hh < 4; ++hh)
#pragma unroll
      for (int r = 0; r < 4; ++r) {
        p[hh][r] = exp2f(st[hh][r] - mo);
        ps += p[hh][r];
      }
    ps += __shfl_xor(ps, 16, 64);
    ps += __shfl_xor(ps, 32, 64);
    lreg += ps;
    // build PV A-fragments via pack + bpermute
    union { unsigned u[4]; bf8_t v; } aw[2];
#pragma unroll
    for (int ks = 0; ks < 2; ++ks) {
      unsigned ch0 = packbf2(p[2 * ks][0], p[2 * ks][1]);
      unsigned ch1 = packbf2(p[2 * ks][2], p[2 * ks][3]);
      unsigned ch2 = packbf2(p[2 * ks + 1][0], p[2 * ks + 1][1]);
      unsigned ch3 = packbf2(p[2 * ks + 1][2], p[2 * ks + 1][3]);
      unsigned t0 = bperm(srcA, ch0), t2 = bperm(srcA, ch2);
      unsigned t1 = bperm(srcA, ch1), t3 = bperm(srcA, ch3);
      unsigned u0 = bperm(srcB, ch0), u2 = bperm(srcB, ch2);
      unsigned u1 = bperm(srcB, ch1), u3 = bperm(srcB, ch3);
      const bool lo = (g < 2);
      aw[ks].u[0] = lo ? t0 : t2;
      aw[ks].u[1] = lo ? t1 : t3;
      aw[ks].u[2] = lo ? u0 : u2;
      aw[ks].u[3] = lo ? u1 : u3;
    }
    // PV (8 MFMA)
    __builtin_amdgcn_s_setprio(1);
#pragma unroll
    for (int d = 0; d < 4; ++d) {
      o[d] = __builtin_amdgcn_mfma_f32_16x16x32_bf16(aw[0].v, bvf[0][d], o[d], 0, 0, 0);
      o[d] = __builtin_amdgcn_mfma_f32_16x16x32_bf16(aw[1].v, bvf[1][d], o[d], 0, 0, 0);
    }
    __builtin_amdgcn_s_setprio(0);
    __syncthreads();
  }
#undef STAGEA

  // epilogue: divide by row sums, write ctx
  float lrr[4];
#pragma unroll
  for (int r = 0; r < 4; ++r) lrr[r] = __shfl(lreg, g * 4 + r, 64);
#pragma unroll
  for (int d = 0; d < 4; ++d)
#pragma unroll
    for (int r = 0; r < 4; ++r) {
      const float v = o[d][r] / lrr[r];
      ctx[((size_t)b * S_ + q0 + g * 4 + r) * M_ + h * 64 + d * 16 + fr] = (__bf16)v;
    }
}

// ---------------- LayerNorm over D=1024, one block per row
__global__ __launch_bounds__(256) void k_ln(const __bf16* __restrict__ hh,
                                            const float* __restrict__ g,
                                            const float* __restrict__ bt,
                                            float* __restrict__ out) {
  const int row = blockIdx.x;
  const int t = threadIdx.x;
  const __bf16* hp = hh + (size_t)row * 1024 + t * 4;
  bf4_t v = *(const bf4_t*)hp;
  float f[4];
  float s1 = 0.f, s2 = 0.f;
#pragma unroll
  for (int j = 0; j < 4; ++j) {
    f[j] = (float)v[j];
    s1 += f[j];
    s2 += f[j] * f[j];
  }
#pragma unroll
  for (int d = 1; d < 64; d <<= 1) {
    s1 += __shfl_xor(s1, d, 64);
    s2 += __shfl_xor(s2, d, 64);
  }
  __shared__ float red[8];
  const int lane = t & 63, wv = t >> 6;
  if (lane == 0) { red[wv] = s1; red[4 + wv] = s2; }
  __syncthreads();
  const float S1 = red[0] + red[1] + red[2] + red[3];
  const float S2 = red[4] + red[5] + red[6] + red[7];
  const float mu = S1 * (1.f / 1024.f);
  const float var = S2 * (1.f / 1024.f) - mu * mu;
  const float inv = rsqrtf(var + 1e-5f);
  float* op = out + (size_t)row * 1024 + t * 4;
#pragma unroll
  for (int j = 0; j < 4; ++j) op[j] = (f[j] - mu) * inv * g[t * 4 + j] + bt[t * 4 + j];
}

extern "C" void kernel_launch(void* const* d_in, const int* in_sizes, int n_in,
                              void* d_out, int out_size, void* d_ws, size_t ws_size,
                              hipStream_t stream) {
  const float* x = (const float*)d_in[0];
  const float* W_enc = (const float*)d_in[1];
  const float* b_enc = (const float*)d_in[2];
  const float* Wq = (const float*)d_in[3];
  const float* bq = (const float*)d_in[4];
  const float* Wk = (const float*)d_in[5];
  const float* bk = (const float*)d_in[6];
  const float* Wv = (const float*)d_in[7];
  const float* bv = (const float*)d_in[8];
  const float* Wo = (const float*)d_in[9];
  const float* bo = (const float*)d_in[10];
  const float* W1 = (const float*)d_in[12];
  const float* b1 = (const float*)d_in[13];
  const float* W2 = (const float*)d_in[14];
  const float* b2 = (const float*)d_in[15];
  const float* lng = (const float*)d_in[16];
  const float* lnb = (const float*)d_in[17];
  float* out = (float*)d_out;

  __bf16* p = (__bf16*)d_ws;
  __bf16* ab = p;  p += (size_t)R_ * 1536;   // [x | attended] bf16, stride 1536
  __bf16* mem = p; p += (size_t)R_ * 512;
  __bf16* qb = p;  p += (size_t)R_ * 512;
  __bf16* pk = p;  p += (size_t)R_ * 512;    // packed-K fragments
  __bf16* pv = p;  p += (size_t)R_ * 512;    // packed-V^T fragments
  __bf16* cx = p;  p += (size_t)R_ * 512;
  __bf16* h1 = p;  p += (size_t)R_ * 1024;
  __bf16* h2 = p;  p += (size_t)R_ * 1024;
  __bf16* WtE = p; p += (size_t)512 * 1024;
  __bf16* WtQ = p; p += (size_t)512 * 512;   // WtQ/WtK/WtV contiguous => fused B
  __bf16* WtK = p; p += (size_t)512 * 512;
  __bf16* WtV = p; p += (size_t)512 * 512;
  __bf16* WtO = p; p += (size_t)512 * 512;
  __bf16* Wt1 = p; p += (size_t)1024 * 1536;
  __bf16* Wt2 = p; p += (size_t)1024 * 1024;

  // 1) merged prep
  PrepArgs pa;
  pa.src[0] = W_enc; pa.dst[0] = WtE; pa.K[0] = 1024; pa.N[0] = 512;
  pa.src[1] = Wq;    pa.dst[1] = WtQ; pa.K[1] = 512;  pa.N[1] = 512;
  pa.src[2] = Wk;    pa.dst[2] = WtK; pa.K[2] = 512;  pa.N[2] = 512;
  pa.src[3] = Wv;    pa.dst[3] = WtV; pa.K[3] = 512;  pa.N[3] = 512;
  pa.src[4] = Wo;    pa.dst[4] = WtO; pa.K[4] = 512;  pa.N[4] = 512;
  pa.src[5] = W1;    pa.dst[5] = Wt1; pa.K[5] = 1536; pa.N[5] = 1024;
  pa.src[6] = W2;    pa.dst[6] = Wt2; pa.K[6] = 1024; pa.N[6] = 1024;
  int acc0 = 0;
  for (int w = 0; w < 7; ++w) {
    pa.start[w] = acc0;
    acc0 += (pa.N[w] >> 5) * (pa.K[w] >> 5);
  }
  pa.start[7] = acc0;  // 4096
  pa.x = x; pa.ab = ab;
  k_prep<<<acc0 + 4096, 256, 0, stream>>>(pa);
  // 2) mem = x @ W_enc + b_enc  (BM=64 -> 512 blocks)
  k_gemm2<64, 0><<<dim3(4, 128), 256, 0, stream>>>(ab, 1536, WtE, b_enc, mem, 512, 1024);
  // 3) fused q,k,v (k,v written fragment-packed)
  k_gemm_qkv<<<dim3(12, 64), 256, 0, stream>>>(mem, WtQ, bq, bk, bv, qb, pk, pv);
  // 4) attention -> cx
  k_attn5<<<1024, 256, 0, stream>>>(qb, pk, pv, cx);
  // 5) attended = cx @ Wo + bo -> ab[:, 1024:1536]  (BM=64 -> 512 blocks)
  k_gemm2<64, 0><<<dim3(4, 128), 256, 0, stream>>>(cx, 512, WtO, bo, ab + 1024, 1536, 512);
  // 6) h1 = gelu([x|att] @ W1 + b1)
  k_gemm2<128, 1><<<dim3(8, 64), 256, 0, stream>>>(ab, 1536, Wt1, b1, h1, 1024, 1536);
  // 7) h2 = h1 @ W2 + b2
  k_gemm2<128, 0><<<dim3(8, 64), 256, 0, stream>>>(h1, 1024, Wt2, b2, h2, 1024, 1024);
  // 8) layernorm -> out (fp32)
  k_ln<<<R_, 256, 0, stream>>>(h2, lng, lnb, out);
}